// Round 3
// baseline (592.002 us; speedup 1.0000x reference)
//
#include <hip/hip_runtime.h>
#include <cstdint>
#include <cstddef>

#define N_NODES   100000
#define N_EDGES   1600000
#define D_IN      128
#define HIDDEN    64
#define N_GRAPHS  512
#define N_CLASSES 10

// ===========================================================================
// Group-split histogram: group g = blockIdx % G counts into its own copy.
// Same grid/block config as fill_kernel so the edge->group mapping matches.
// ===========================================================================
__global__ __launch_bounds__(256)
void hist_kernel(const int* __restrict__ dst, int* __restrict__ degi,
                 int n_edges, int n_nodes, int G) {
    int t = blockIdx.x * 256 + threadIdx.x;
    if (t >= n_edges) return;
    int g = blockIdx.x % G;
    atomicAdd(&degi[(size_t)g * n_nodes + dst[t]], 1);
}

// dinv[n] = rsqrt(sum_g degi[g][n] + 1)
__global__ void dinv_sum_kernel(const int* __restrict__ degi, float* __restrict__ dinv,
                                int n_nodes, int G) {
    int t = blockIdx.x * blockDim.x + threadIdx.x;
    if (t >= n_nodes) return;
    int s = 0;
    for (int g = 0; g < G; g++) s += degi[(size_t)g * n_nodes + t];
    dinv[t] = rsqrtf((float)s + 1.0f);
}

// ===========================================================================
// Exclusive prefix scan over degi (flattened, length n = G*N_NODES)
// 4096 elems per 256-thread block, 3 passes. scan3 writes offs AND cursor.
// ===========================================================================
__global__ __launch_bounds__(256)
void scan1_kernel(const int* __restrict__ degi, int* __restrict__ bsum, int n) {
    __shared__ int lds[256];
    int tid = threadIdx.x;
    int base = blockIdx.x * 4096 + tid * 16;
    int s = 0;
#pragma unroll
    for (int j = 0; j < 16; j++) { int i = base + j; if (i < n) s += degi[i]; }
    lds[tid] = s; __syncthreads();
    for (int off = 128; off > 0; off >>= 1) {
        if (tid < off) lds[tid] += lds[tid + off];
        __syncthreads();
    }
    if (tid == 0) bsum[blockIdx.x] = lds[0];
}

// single block: exclusive scan of bsum (nb <= 256); writes offs[n] = total
__global__ __launch_bounds__(256)
void scan2_kernel(int* __restrict__ bsum, int* __restrict__ offs, int nb, int n) {
    __shared__ int lds[256];
    int tid = threadIdx.x;
    int v = (tid < nb) ? bsum[tid] : 0;
    lds[tid] = v; __syncthreads();
    for (int off = 1; off < 256; off <<= 1) {
        int t = (tid >= off) ? lds[tid - off] : 0;
        __syncthreads();
        lds[tid] += t;
        __syncthreads();
    }
    if (tid < nb) bsum[tid] = lds[tid] - v;   // exclusive block offsets
    if (tid == 255) offs[n] = lds[255];       // grand total (== n_edges)
}

__global__ __launch_bounds__(256)
void scan3_kernel(const int* __restrict__ degi, const int* __restrict__ bsum,
                  int* __restrict__ offs, int* __restrict__ cursor, int n) {
    __shared__ int lds[256];
    int tid = threadIdx.x;
    int base = blockIdx.x * 4096 + tid * 16;
    int v[16]; int s = 0;
#pragma unroll
    for (int j = 0; j < 16; j++) {
        int i = base + j;
        v[j] = (i < n) ? degi[i] : 0;
        s += v[j];
    }
    lds[tid] = s; __syncthreads();
    for (int off = 1; off < 256; off <<= 1) {
        int t = (tid >= off) ? lds[tid - off] : 0;
        __syncthreads();
        lds[tid] += t;
        __syncthreads();
    }
    int ex = lds[tid] - s + bsum[blockIdx.x];
#pragma unroll
    for (int j = 0; j < 16; j++) {
        int i = base + j;
        if (i < n) { offs[i] = ex; cursor[i] = ex; ex += v[j]; }
    }
}

// ===========================================================================
// Bucket fill: group g = blockIdx % G writes only into its contiguous srcs
// region (group-major layout) -> XCD-local lines, 8x less cursor contention.
// ===========================================================================
__global__ __launch_bounds__(256)
void fill_kernel(const int* __restrict__ src, const int* __restrict__ dst,
                 int* __restrict__ cursor, int* __restrict__ srcs_sorted,
                 int n_edges, int n_nodes, int G) {
    int t = blockIdx.x * 256 + threadIdx.x;
    if (t >= n_edges) return;
    int g = blockIdx.x % G;
    int d = dst[t];
    int pos = atomicAdd(&cursor[(size_t)g * n_nodes + d], 1);
    srcs_sorted[pos] = src[t];
}

// ===========================================================================
// GEMM: H[n_rows x 64] = X[n_rows x K] @ W[K x 64]
// ===========================================================================
template <int K>
__global__ __launch_bounds__(256)
void gemm64_kernel(const float* __restrict__ X, const float* __restrict__ W,
                   float* __restrict__ H, int n_rows) {
    __shared__ float Xs[64][K + 4];
    __shared__ float Ws[K][64];

    const int tid  = threadIdx.x;
    const int row0 = blockIdx.x * 64;

    constexpr int WN4 = K * 64 / 4;
    const float4* W4 = (const float4*)W;
    float4* Ws4 = (float4*)&Ws[0][0];
    for (int i = tid; i < WN4; i += 256) Ws4[i] = W4[i];

    constexpr int KQ = K / 4;
    for (int i = tid; i < 64 * KQ; i += 256) {
        int r  = i / KQ;
        int k4 = i % KQ;
        int row = row0 + r;
        float4 v = make_float4(0.f, 0.f, 0.f, 0.f);
        if (row < n_rows) v = ((const float4*)(X + (size_t)row * K))[k4];
        *(float4*)&Xs[r][k4 * 4] = v;
    }
    __syncthreads();

    const int cg = (tid & 15) * 4;
    const int rg = (tid >> 4) * 4;

    float4 acc0 = make_float4(0.f,0.f,0.f,0.f);
    float4 acc1 = make_float4(0.f,0.f,0.f,0.f);
    float4 acc2 = make_float4(0.f,0.f,0.f,0.f);
    float4 acc3 = make_float4(0.f,0.f,0.f,0.f);

#pragma unroll 8
    for (int k = 0; k < K; k++) {
        float4 w = *(const float4*)&Ws[k][cg];
        float x0 = Xs[rg + 0][k];
        float x1 = Xs[rg + 1][k];
        float x2 = Xs[rg + 2][k];
        float x3 = Xs[rg + 3][k];
        acc0.x += x0 * w.x; acc0.y += x0 * w.y; acc0.z += x0 * w.z; acc0.w += x0 * w.w;
        acc1.x += x1 * w.x; acc1.y += x1 * w.y; acc1.z += x1 * w.z; acc1.w += x1 * w.w;
        acc2.x += x2 * w.x; acc2.y += x2 * w.y; acc2.z += x2 * w.z; acc2.w += x2 * w.w;
        acc3.x += x3 * w.x; acc3.y += x3 * w.y; acc3.z += x3 * w.z; acc3.w += x3 * w.w;
    }

    float4 accs[4] = {acc0, acc1, acc2, acc3};
#pragma unroll
    for (int i = 0; i < 4; i++) {
        int row = row0 + rg + i;
        if (row < n_rows) *(float4*)(H + (size_t)row * 64 + cg) = accs[i];
    }
}

// ===========================================================================
// Segmented CSR gather (G segments per node), fused self-loop + bias + relu.
// 16 lanes per node, 4 channels each.
// ===========================================================================
__global__ __launch_bounds__(256)
void gather_agg_kernel(const int* __restrict__ offs, const int* __restrict__ srcs_sorted,
                       const float* __restrict__ dinv, const float* __restrict__ h,
                       const float* __restrict__ b, float* __restrict__ out,
                       int n_nodes, int G) {
    int t = blockIdx.x * blockDim.x + threadIdx.x;
    int node = t >> 4;
    if (node >= n_nodes) return;
    int cg = (t & 15) * 4;

    float dn = dinv[node];
    float c2 = dn * dn;
    float4 hv = *(const float4*)(h + (size_t)node * 64 + cg);
    float4 acc;
    acc.x = hv.x * c2; acc.y = hv.y * c2; acc.z = hv.z * c2; acc.w = hv.w * c2;

    for (int g = 0; g < G; g++) {
        int i0 = offs[(size_t)g * n_nodes + node];
        int i1 = offs[(size_t)g * n_nodes + node + 1];
        for (int i = i0; i < i1; i++) {
            int s = srcs_sorted[i];
            float c = dinv[s] * dn;
            float4 v = *(const float4*)(h + (size_t)s * 64 + cg);
            acc.x += v.x * c; acc.y += v.y * c; acc.z += v.z * c; acc.w += v.w * c;
        }
    }

    float4 bv = *(const float4*)(b + cg);
    float4 r;
    r.x = fmaxf(acc.x + bv.x, 0.f);
    r.y = fmaxf(acc.y + bv.y, 0.f);
    r.z = fmaxf(acc.z + bv.z, 0.f);
    r.w = fmaxf(acc.w + bv.w, 0.f);
    *(float4*)(out + (size_t)node * 64 + cg) = r;
}

// ===========================================================================
// Pooling (batch sorted) + head
// ===========================================================================
__global__ __launch_bounds__(256)
void pool_kernel(const float* __restrict__ h, const int* __restrict__ batch,
                 float* __restrict__ pooled, float* __restrict__ cnt,
                 int n_nodes, int chunk) {
    int wave = (blockIdx.x * blockDim.x + threadIdx.x) >> 6;
    int lane = threadIdx.x & 63;
    int start = wave * chunk;
    if (start >= n_nodes) return;
    int end = min(start + chunk, n_nodes);

    int cur = batch[start];
    float acc = 0.f;
    float c = 0.f;
    for (int i = start; i < end; i++) {
        int g = batch[i];
        if (g != cur) {
            unsafeAtomicAdd(&pooled[(size_t)cur * 64 + lane], acc);
            if (lane == 0) unsafeAtomicAdd(&cnt[cur], c);
            acc = 0.f; c = 0.f; cur = g;
        }
        acc += h[(size_t)i * 64 + lane];
        c += 1.f;
    }
    unsafeAtomicAdd(&pooled[(size_t)cur * 64 + lane], acc);
    if (lane == 0) unsafeAtomicAdd(&cnt[cur], c);
}

__global__ __launch_bounds__(256)
void head_kernel(const float* __restrict__ pooled, const float* __restrict__ cnt,
                 const float* __restrict__ Wfc, const float* __restrict__ bfc,
                 float* __restrict__ out) {
    __shared__ float Ws[HIDDEN * N_CLASSES];
    __shared__ float bs[N_CLASSES];
    int tid = threadIdx.x;
    for (int i = tid; i < HIDDEN * N_CLASSES; i += 256) Ws[i] = Wfc[i];
    if (tid < N_CLASSES) bs[tid] = bfc[tid];
    __syncthreads();

    int g = blockIdx.x * 256 + tid;
    if (g >= N_GRAPHS) return;

    float inv = 1.f / fmaxf(cnt[g], 1.f);
    float p[HIDDEN];
#pragma unroll
    for (int k = 0; k < HIDDEN; k++) p[k] = pooled[(size_t)g * 64 + k] * inv;

    float lg[N_CLASSES];
    float m = -1e30f;
#pragma unroll
    for (int j = 0; j < N_CLASSES; j++) {
        float a = bs[j];
#pragma unroll
        for (int k = 0; k < HIDDEN; k++) a += p[k] * Ws[k * N_CLASSES + j];
        lg[j] = a;
        m = fmaxf(m, a);
    }
    float s = 0.f;
#pragma unroll
    for (int j = 0; j < N_CLASSES; j++) s += __expf(lg[j] - m);
    float lse = m + __logf(s);
#pragma unroll
    for (int j = 0; j < N_CLASSES; j++) out[(size_t)g * N_CLASSES + j] = lg[j] - lse;
}

// ===========================================================================
// Launch
// ===========================================================================
extern "C" void kernel_launch(void* const* d_in, const int* in_sizes, int n_in,
                              void* d_out, int out_size, void* d_ws, size_t ws_size,
                              hipStream_t stream) {
    const float* x   = (const float*)d_in[0];
    const int*   ei  = (const int*)d_in[1];
    const int*   bat = (const int*)d_in[2];
    const float* W1  = (const float*)d_in[3];
    const float* b1  = (const float*)d_in[4];
    const float* W2  = (const float*)d_in[5];
    const float* b2  = (const float*)d_in[6];
    const float* Wfc = (const float*)d_in[7];
    const float* bfc = (const float*)d_in[8];
    float* out = (float*)d_out;

    const int* src = ei;
    const int* dst = ei + N_EDGES;

    char* ws = (char*)d_ws;

    // NEEDED(G) = 58,135,184 + 800,000*G   (layout below)
    int G;
    if      (ws_size >= 58135184 + 800000 * (size_t)8) G = 8;
    else if (ws_size >= 58135184 + 800000 * (size_t)2) G = 2;
    else                                               G = 1;  // == proven round-2 footprint

    const size_t OFF_BUFA = 0;                                   // 25,600,000
    const size_t OFF_BUFB = 25600000;                            // 25,600,000
    const size_t OFF_DINV = 51200000;                            //    400,000
    const size_t OFF_OFFS = 51600000;                            // G*400,000 + 16
    const size_t OFF_CURS = OFF_OFFS + (size_t)G * 400000 + 16;  // G*400,000  (also degi)
    const size_t OFF_BSUM = OFF_CURS + (size_t)G * 400000;       //      2,048
    const size_t OFF_POOL = OFF_BSUM + 2048;                     //    131,072
    const size_t OFF_CNT  = OFF_POOL + 131072;                   //      2,048
    const size_t OFF_SRCS = OFF_CNT + 2048;                      //  6,400,000

    float* bufA   = (float*)(ws + OFF_BUFA);
    float* bufB   = (float*)(ws + OFF_BUFB);
    float* dinv   = (float*)(ws + OFF_DINV);
    int*   offs   = (int*)  (ws + OFF_OFFS);
    int*   degi   = (int*)  (ws + OFF_CURS);   // histogram, then cursor
    int*   bsum   = (int*)  (ws + OFF_BSUM);
    float* pooled = (float*)(ws + OFF_POOL);
    float* cnt    = (float*)(ws + OFF_CNT);
    int*   srcs   = (int*)  (ws + OFF_SRCS);

    const int GN = G * N_NODES;
    const int SCAN_BLOCKS = (GN + 4095) / 4096;     // G=8 -> 196 (<=256 ok)
    const int EDGE_BLOCKS = (N_EDGES + 255) / 256;  // 6250

    // --- build group-split CSR (reused by both layers) ---
    hipMemsetAsync(degi, 0, (size_t)GN * sizeof(int), stream);
    hist_kernel<<<EDGE_BLOCKS, 256, 0, stream>>>(dst, degi, N_EDGES, N_NODES, G);
    dinv_sum_kernel<<<(N_NODES + 255) / 256, 256, 0, stream>>>(degi, dinv, N_NODES, G);
    scan1_kernel<<<SCAN_BLOCKS, 256, 0, stream>>>(degi, bsum, GN);
    scan2_kernel<<<1, 256, 0, stream>>>(bsum, offs, SCAN_BLOCKS, GN);
    // scan3 writes offs and initializes cursor in one pass (cursor aliases degi:
    // scan3 reads degi[i] before writing cursor[i] at the same index -> safe).
    scan3_kernel<<<SCAN_BLOCKS, 256, 0, stream>>>(degi, bsum, offs, degi, GN);
    fill_kernel<<<EDGE_BLOCKS, 256, 0, stream>>>(src, dst, degi, srcs, N_EDGES, N_NODES, G);

    // --- layer 1 ---
    gemm64_kernel<D_IN><<<(N_NODES + 63) / 64, 256, 0, stream>>>(x, W1, bufA, N_NODES);
    gather_agg_kernel<<<(N_NODES * 16 + 255) / 256, 256, 0, stream>>>(
        offs, srcs, dinv, bufA, b1, bufB, N_NODES, G);

    // --- layer 2 ---
    gemm64_kernel<HIDDEN><<<(N_NODES + 63) / 64, 256, 0, stream>>>(bufB, W2, bufA, N_NODES);
    gather_agg_kernel<<<(N_NODES * 16 + 255) / 256, 256, 0, stream>>>(
        offs, srcs, dinv, bufA, b2, bufB, N_NODES, G);

    // --- pooling + head ---
    hipMemsetAsync(pooled, 0, (size_t)N_GRAPHS * 64 * sizeof(float), stream);
    hipMemsetAsync(cnt, 0, (size_t)N_GRAPHS * sizeof(float), stream);
    {
        const int chunk = 256;
        int waves  = (N_NODES + chunk - 1) / chunk;
        int blocks = (waves + 3) / 4;
        pool_kernel<<<blocks, 256, 0, stream>>>(bufB, bat, pooled, cnt, N_NODES, chunk);
    }
    head_kernel<<<(N_GRAPHS + 255) / 256, 256, 0, stream>>>(pooled, cnt, Wfc, bfc, out);
}

// Round 4
// 512.250 us; speedup vs baseline: 1.1557x; 1.1557x over previous
//
#include <hip/hip_runtime.h>
#include <cstdint>
#include <cstddef>

#define N_NODES   100000
#define N_EDGES   1600000
#define D_IN      128
#define HIDDEN    64
#define N_GRAPHS  512
#define N_CLASSES 10

// ===========================================================================
// Group-split histogram: group g = blockIdx % G counts into its own copy.
// Same grid/block config as fill_kernel so the edge->group mapping matches.
// ===========================================================================
__global__ __launch_bounds__(256)
void hist_kernel(const int* __restrict__ dst, int* __restrict__ degi,
                 int n_edges, int n_nodes, int G) {
    int t = blockIdx.x * 256 + threadIdx.x;
    if (t >= n_edges) return;
    int g = blockIdx.x % G;
    atomicAdd(&degi[(size_t)g * n_nodes + dst[t]], 1);
}

// dinv[n] = rsqrt(sum_g degi[g][n] + 1)
__global__ void dinv_sum_kernel(const int* __restrict__ degi, float* __restrict__ dinv,
                                int n_nodes, int G) {
    int t = blockIdx.x * blockDim.x + threadIdx.x;
    if (t >= n_nodes) return;
    int s = 0;
    for (int g = 0; g < G; g++) s += degi[(size_t)g * n_nodes + t];
    dinv[t] = rsqrtf((float)s + 1.0f);
}

// ===========================================================================
// Exclusive prefix scan over degi (flattened, length n = G*N_NODES)
// 4096 elems per 256-thread block, 3 passes. scan3 writes offs AND cursor.
// ===========================================================================
__global__ __launch_bounds__(256)
void scan1_kernel(const int* __restrict__ degi, int* __restrict__ bsum, int n) {
    __shared__ int lds[256];
    int tid = threadIdx.x;
    int base = blockIdx.x * 4096 + tid * 16;
    int s = 0;
#pragma unroll
    for (int j = 0; j < 16; j++) { int i = base + j; if (i < n) s += degi[i]; }
    lds[tid] = s; __syncthreads();
    for (int off = 128; off > 0; off >>= 1) {
        if (tid < off) lds[tid] += lds[tid + off];
        __syncthreads();
    }
    if (tid == 0) bsum[blockIdx.x] = lds[0];
}

// single block: exclusive scan of bsum (nb <= 256); writes offs[n] = total
__global__ __launch_bounds__(256)
void scan2_kernel(int* __restrict__ bsum, int* __restrict__ offs, int nb, int n) {
    __shared__ int lds[256];
    int tid = threadIdx.x;
    int v = (tid < nb) ? bsum[tid] : 0;
    lds[tid] = v; __syncthreads();
    for (int off = 1; off < 256; off <<= 1) {
        int t = (tid >= off) ? lds[tid - off] : 0;
        __syncthreads();
        lds[tid] += t;
        __syncthreads();
    }
    if (tid < nb) bsum[tid] = lds[tid] - v;   // exclusive block offsets
    if (tid == 255) offs[n] = lds[255];       // grand total (== n_edges)
}

__global__ __launch_bounds__(256)
void scan3_kernel(const int* __restrict__ degi, const int* __restrict__ bsum,
                  int* __restrict__ offs, int* __restrict__ cursor, int n) {
    __shared__ int lds[256];
    int tid = threadIdx.x;
    int base = blockIdx.x * 4096 + tid * 16;
    int v[16]; int s = 0;
#pragma unroll
    for (int j = 0; j < 16; j++) {
        int i = base + j;
        v[j] = (i < n) ? degi[i] : 0;
        s += v[j];
    }
    lds[tid] = s; __syncthreads();
    for (int off = 1; off < 256; off <<= 1) {
        int t = (tid >= off) ? lds[tid - off] : 0;
        __syncthreads();
        lds[tid] += t;
        __syncthreads();
    }
    int ex = lds[tid] - s + bsum[blockIdx.x];
#pragma unroll
    for (int j = 0; j < 16; j++) {
        int i = base + j;
        if (i < n) { offs[i] = ex; cursor[i] = ex; ex += v[j]; }
    }
}

// ===========================================================================
// Bucket fill: group g = blockIdx % G writes only into its contiguous srcs
// region (group-major layout) -> XCD-local lines, 8x less cursor contention.
// ===========================================================================
__global__ __launch_bounds__(256)
void fill_kernel(const int* __restrict__ src, const int* __restrict__ dst,
                 int* __restrict__ cursor, int* __restrict__ srcs_sorted,
                 int n_edges, int n_nodes, int G) {
    int t = blockIdx.x * 256 + threadIdx.x;
    if (t >= n_edges) return;
    int g = blockIdx.x % G;
    int d = dst[t];
    int pos = atomicAdd(&cursor[(size_t)g * n_nodes + d], 1);
    srcs_sorted[pos] = src[t];
}

// ===========================================================================
// GEMM: H[n_rows x 64] = X[n_rows x K] @ W[K x 64]
// ===========================================================================
template <int K>
__global__ __launch_bounds__(256)
void gemm64_kernel(const float* __restrict__ X, const float* __restrict__ W,
                   float* __restrict__ H, int n_rows) {
    __shared__ float Xs[64][K + 4];
    __shared__ float Ws[K][64];

    const int tid  = threadIdx.x;
    const int row0 = blockIdx.x * 64;

    constexpr int WN4 = K * 64 / 4;
    const float4* W4 = (const float4*)W;
    float4* Ws4 = (float4*)&Ws[0][0];
    for (int i = tid; i < WN4; i += 256) Ws4[i] = W4[i];

    constexpr int KQ = K / 4;
    for (int i = tid; i < 64 * KQ; i += 256) {
        int r  = i / KQ;
        int k4 = i % KQ;
        int row = row0 + r;
        float4 v = make_float4(0.f, 0.f, 0.f, 0.f);
        if (row < n_rows) v = ((const float4*)(X + (size_t)row * K))[k4];
        *(float4*)&Xs[r][k4 * 4] = v;
    }
    __syncthreads();

    const int cg = (tid & 15) * 4;
    const int rg = (tid >> 4) * 4;

    float4 acc0 = make_float4(0.f,0.f,0.f,0.f);
    float4 acc1 = make_float4(0.f,0.f,0.f,0.f);
    float4 acc2 = make_float4(0.f,0.f,0.f,0.f);
    float4 acc3 = make_float4(0.f,0.f,0.f,0.f);

#pragma unroll 8
    for (int k = 0; k < K; k++) {
        float4 w = *(const float4*)&Ws[k][cg];
        float x0 = Xs[rg + 0][k];
        float x1 = Xs[rg + 1][k];
        float x2 = Xs[rg + 2][k];
        float x3 = Xs[rg + 3][k];
        acc0.x += x0 * w.x; acc0.y += x0 * w.y; acc0.z += x0 * w.z; acc0.w += x0 * w.w;
        acc1.x += x1 * w.x; acc1.y += x1 * w.y; acc1.z += x1 * w.z; acc1.w += x1 * w.w;
        acc2.x += x2 * w.x; acc2.y += x2 * w.y; acc2.z += x2 * w.z; acc2.w += x2 * w.w;
        acc3.x += x3 * w.x; acc3.y += x3 * w.y; acc3.z += x3 * w.z; acc3.w += x3 * w.w;
    }

    float4 accs[4] = {acc0, acc1, acc2, acc3};
#pragma unroll
    for (int i = 0; i < 4; i++) {
        int row = row0 + rg + i;
        if (row < n_rows) *(float4*)(H + (size_t)row * 64 + cg) = accs[i];
    }
}

// ===========================================================================
// Segmented CSR gather (G segments per node), fused self-loop + bias + relu.
// 16 lanes per node, 4 channels each.
// ===========================================================================
__global__ __launch_bounds__(256)
void gather_agg_kernel(const int* __restrict__ offs, const int* __restrict__ srcs_sorted,
                       const float* __restrict__ dinv, const float* __restrict__ h,
                       const float* __restrict__ b, float* __restrict__ out,
                       int n_nodes, int G) {
    int t = blockIdx.x * blockDim.x + threadIdx.x;
    int node = t >> 4;
    if (node >= n_nodes) return;
    int cg = (t & 15) * 4;

    float dn = dinv[node];
    float c2 = dn * dn;
    float4 hv = *(const float4*)(h + (size_t)node * 64 + cg);
    float4 acc;
    acc.x = hv.x * c2; acc.y = hv.y * c2; acc.z = hv.z * c2; acc.w = hv.w * c2;

    for (int g = 0; g < G; g++) {
        int i0 = offs[(size_t)g * n_nodes + node];
        int i1 = offs[(size_t)g * n_nodes + node + 1];
        for (int i = i0; i < i1; i++) {
            int s = srcs_sorted[i];
            float c = dinv[s] * dn;
            float4 v = *(const float4*)(h + (size_t)s * 64 + cg);
            acc.x += v.x * c; acc.y += v.y * c; acc.z += v.z * c; acc.w += v.w * c;
        }
    }

    float4 bv = *(const float4*)(b + cg);
    float4 r;
    r.x = fmaxf(acc.x + bv.x, 0.f);
    r.y = fmaxf(acc.y + bv.y, 0.f);
    r.z = fmaxf(acc.z + bv.z, 0.f);
    r.w = fmaxf(acc.w + bv.w, 0.f);
    *(float4*)(out + (size_t)node * 64 + cg) = r;
}

// ===========================================================================
// Pooling (batch sorted): one wave per chunk of nodes; lane = channel.
// chunk=32 -> 3125 waves so the 256-CU chip is actually occupied.
// ===========================================================================
__global__ __launch_bounds__(256)
void pool_kernel(const float* __restrict__ h, const int* __restrict__ batch,
                 float* __restrict__ pooled, float* __restrict__ cnt,
                 int n_nodes, int chunk) {
    int wave = (blockIdx.x * blockDim.x + threadIdx.x) >> 6;
    int lane = threadIdx.x & 63;
    int start = wave * chunk;
    if (start >= n_nodes) return;
    int end = min(start + chunk, n_nodes);

    int cur = batch[start];
    float acc = 0.f;
    float c = 0.f;
    for (int i = start; i < end; i++) {
        int g = batch[i];
        if (g != cur) {
            unsafeAtomicAdd(&pooled[(size_t)cur * 64 + lane], acc);
            if (lane == 0) unsafeAtomicAdd(&cnt[cur], c);
            acc = 0.f; c = 0.f; cur = g;
        }
        acc += h[(size_t)i * 64 + lane];
        c += 1.f;
    }
    unsafeAtomicAdd(&pooled[(size_t)cur * 64 + lane], acc);
    if (lane == 0) unsafeAtomicAdd(&cnt[cur], c);
}

__global__ __launch_bounds__(256)
void head_kernel(const float* __restrict__ pooled, const float* __restrict__ cnt,
                 const float* __restrict__ Wfc, const float* __restrict__ bfc,
                 float* __restrict__ out) {
    __shared__ float Ws[HIDDEN * N_CLASSES];
    __shared__ float bs[N_CLASSES];
    int tid = threadIdx.x;
    for (int i = tid; i < HIDDEN * N_CLASSES; i += 256) Ws[i] = Wfc[i];
    if (tid < N_CLASSES) bs[tid] = bfc[tid];
    __syncthreads();

    int g = blockIdx.x * 256 + tid;
    if (g >= N_GRAPHS) return;

    float inv = 1.f / fmaxf(cnt[g], 1.f);
    float p[HIDDEN];
#pragma unroll
    for (int k = 0; k < HIDDEN; k++) p[k] = pooled[(size_t)g * 64 + k] * inv;

    float lg[N_CLASSES];
    float m = -1e30f;
#pragma unroll
    for (int j = 0; j < N_CLASSES; j++) {
        float a = bs[j];
#pragma unroll
        for (int k = 0; k < HIDDEN; k++) a += p[k] * Ws[k * N_CLASSES + j];
        lg[j] = a;
        m = fmaxf(m, a);
    }
    float s = 0.f;
#pragma unroll
    for (int j = 0; j < N_CLASSES; j++) s += __expf(lg[j] - m);
    float lse = m + __logf(s);
#pragma unroll
    for (int j = 0; j < N_CLASSES; j++) out[(size_t)g * N_CLASSES + j] = lg[j] - lse;
}

// ===========================================================================
// Launch
// ===========================================================================
extern "C" void kernel_launch(void* const* d_in, const int* in_sizes, int n_in,
                              void* d_out, int out_size, void* d_ws, size_t ws_size,
                              hipStream_t stream) {
    const float* x   = (const float*)d_in[0];
    const int*   ei  = (const int*)d_in[1];
    const int*   bat = (const int*)d_in[2];
    const float* W1  = (const float*)d_in[3];
    const float* b1  = (const float*)d_in[4];
    const float* W2  = (const float*)d_in[5];
    const float* b2  = (const float*)d_in[6];
    const float* Wfc = (const float*)d_in[7];
    const float* bfc = (const float*)d_in[8];
    float* out = (float*)d_out;

    const int* src = ei;
    const int* dst = ei + N_EDGES;

    char* ws = (char*)d_ws;

    // NEEDED(G) = 58,135,184 + 800,000*G   (layout below)
    int G;
    if      (ws_size >= 58135184 + 800000 * (size_t)8) G = 8;
    else if (ws_size >= 58135184 + 800000 * (size_t)2) G = 2;
    else                                               G = 1;  // == proven round-2 footprint

    const size_t OFF_BUFA = 0;                                   // 25,600,000
    const size_t OFF_BUFB = 25600000;                            // 25,600,000
    const size_t OFF_DINV = 51200000;                            //    400,000
    const size_t OFF_OFFS = 51600000;                            // G*400,000 + 16
    const size_t OFF_CURS = OFF_OFFS + (size_t)G * 400000 + 16;  // G*400,000  (also degi)
    const size_t OFF_BSUM = OFF_CURS + (size_t)G * 400000;       //      2,048
    const size_t OFF_POOL = OFF_BSUM + 2048;                     //    131,072
    const size_t OFF_CNT  = OFF_POOL + 131072;                   //      2,048
    const size_t OFF_SRCS = OFF_CNT + 2048;                      //  6,400,000

    float* bufA   = (float*)(ws + OFF_BUFA);
    float* bufB   = (float*)(ws + OFF_BUFB);
    float* dinv   = (float*)(ws + OFF_DINV);
    int*   offs   = (int*)  (ws + OFF_OFFS);
    int*   degi   = (int*)  (ws + OFF_CURS);   // histogram, then cursor
    int*   bsum   = (int*)  (ws + OFF_BSUM);
    float* pooled = (float*)(ws + OFF_POOL);
    float* cnt    = (float*)(ws + OFF_CNT);
    int*   srcs   = (int*)  (ws + OFF_SRCS);

    const int GN = G * N_NODES;
    const int SCAN_BLOCKS = (GN + 4095) / 4096;     // G=8 -> 196 (<=256 ok)
    const int EDGE_BLOCKS = (N_EDGES + 255) / 256;  // 6250

    // --- build group-split CSR (reused by both layers) ---
    hipMemsetAsync(degi, 0, (size_t)GN * sizeof(int), stream);
    hist_kernel<<<EDGE_BLOCKS, 256, 0, stream>>>(dst, degi, N_EDGES, N_NODES, G);
    dinv_sum_kernel<<<(N_NODES + 255) / 256, 256, 0, stream>>>(degi, dinv, N_NODES, G);
    scan1_kernel<<<SCAN_BLOCKS, 256, 0, stream>>>(degi, bsum, GN);
    scan2_kernel<<<1, 256, 0, stream>>>(bsum, offs, SCAN_BLOCKS, GN);
    // scan3 writes offs and initializes cursor in one pass (cursor aliases degi:
    // scan3 reads degi[i] before writing cursor[i] at the same index -> safe).
    scan3_kernel<<<SCAN_BLOCKS, 256, 0, stream>>>(degi, bsum, offs, degi, GN);
    fill_kernel<<<EDGE_BLOCKS, 256, 0, stream>>>(src, dst, degi, srcs, N_EDGES, N_NODES, G);

    // --- layer 1 ---
    gemm64_kernel<D_IN><<<(N_NODES + 63) / 64, 256, 0, stream>>>(x, W1, bufA, N_NODES);
    gather_agg_kernel<<<(N_NODES * 16 + 255) / 256, 256, 0, stream>>>(
        offs, srcs, dinv, bufA, b1, bufB, N_NODES, G);

    // --- layer 2 ---
    gemm64_kernel<HIDDEN><<<(N_NODES + 63) / 64, 256, 0, stream>>>(bufB, W2, bufA, N_NODES);
    gather_agg_kernel<<<(N_NODES * 16 + 255) / 256, 256, 0, stream>>>(
        offs, srcs, dinv, bufA, b2, bufB, N_NODES, G);

    // --- pooling + head ---
    hipMemsetAsync(pooled, 0, (size_t)N_GRAPHS * 64 * sizeof(float), stream);
    hipMemsetAsync(cnt, 0, (size_t)N_GRAPHS * sizeof(float), stream);
    {
        const int chunk = 32;   // 3125 waves -> ~12 waves/CU (was 256 -> 391 waves, 3.5% occ)
        int waves  = (N_NODES + chunk - 1) / chunk;
        int blocks = (waves + 3) / 4;
        pool_kernel<<<blocks, 256, 0, stream>>>(bufB, bat, pooled, cnt, N_NODES, chunk);
    }
    head_kernel<<<(N_GRAPHS + 255) / 256, 256, 0, stream>>>(pooled, cnt, Wfc, bfc, out);
}

// Round 5
// 478.158 us; speedup vs baseline: 1.2381x; 1.0713x over previous
//
#include <hip/hip_runtime.h>
#include <cstdint>
#include <cstddef>

#define N_NODES   100000
#define N_EDGES   1600000
#define D_IN      128
#define HIDDEN    64
#define N_GRAPHS  512
#define N_CLASSES 10

// ---- bf16 helpers (RNE pack, bit-shift unpack) ----
__device__ inline float bf2f(unsigned short u) {
    return __uint_as_float(((unsigned int)u) << 16);
}
__device__ inline unsigned short f2bf(float f) {
    unsigned int x = __float_as_uint(f);
    return (unsigned short)((x + 0x7FFF + ((x >> 16) & 1)) >> 16);
}

// ===========================================================================
// Group-split histogram: group g = blockIdx % G counts into its own copy.
// Same grid/block config as fill_kernel so the edge->group mapping matches.
// ===========================================================================
__global__ __launch_bounds__(256)
void hist_kernel(const int* __restrict__ dst, int* __restrict__ degi,
                 int n_edges, int n_nodes, int G) {
    int t = blockIdx.x * 256 + threadIdx.x;
    if (t >= n_edges) return;
    int g = blockIdx.x % G;
    atomicAdd(&degi[(size_t)g * n_nodes + dst[t]], 1);
}

// dinv[n] = rsqrt(sum_g degi[g][n] + 1)
__global__ void dinv_sum_kernel(const int* __restrict__ degi, float* __restrict__ dinv,
                                int n_nodes, int G) {
    int t = blockIdx.x * blockDim.x + threadIdx.x;
    if (t >= n_nodes) return;
    int s = 0;
    for (int g = 0; g < G; g++) s += degi[(size_t)g * n_nodes + t];
    dinv[t] = rsqrtf((float)s + 1.0f);
}

// ===========================================================================
// Exclusive prefix scan over degi (flattened, length n = G*N_NODES)
// 4096 elems per 256-thread block, 3 passes. scan3 writes offs AND cursor.
// ===========================================================================
__global__ __launch_bounds__(256)
void scan1_kernel(const int* __restrict__ degi, int* __restrict__ bsum, int n) {
    __shared__ int lds[256];
    int tid = threadIdx.x;
    int base = blockIdx.x * 4096 + tid * 16;
    int s = 0;
#pragma unroll
    for (int j = 0; j < 16; j++) { int i = base + j; if (i < n) s += degi[i]; }
    lds[tid] = s; __syncthreads();
    for (int off = 128; off > 0; off >>= 1) {
        if (tid < off) lds[tid] += lds[tid + off];
        __syncthreads();
    }
    if (tid == 0) bsum[blockIdx.x] = lds[0];
}

__global__ __launch_bounds__(256)
void scan2_kernel(int* __restrict__ bsum, int* __restrict__ offs, int nb, int n) {
    __shared__ int lds[256];
    int tid = threadIdx.x;
    int v = (tid < nb) ? bsum[tid] : 0;
    lds[tid] = v; __syncthreads();
    for (int off = 1; off < 256; off <<= 1) {
        int t = (tid >= off) ? lds[tid - off] : 0;
        __syncthreads();
        lds[tid] += t;
        __syncthreads();
    }
    if (tid < nb) bsum[tid] = lds[tid] - v;   // exclusive block offsets
    if (tid == 255) offs[n] = lds[255];       // grand total (== n_edges)
}

__global__ __launch_bounds__(256)
void scan3_kernel(const int* __restrict__ degi, const int* __restrict__ bsum,
                  int* __restrict__ offs, int* __restrict__ cursor, int n) {
    __shared__ int lds[256];
    int tid = threadIdx.x;
    int base = blockIdx.x * 4096 + tid * 16;
    int v[16]; int s = 0;
#pragma unroll
    for (int j = 0; j < 16; j++) {
        int i = base + j;
        v[j] = (i < n) ? degi[i] : 0;
        s += v[j];
    }
    lds[tid] = s; __syncthreads();
    for (int off = 1; off < 256; off <<= 1) {
        int t = (tid >= off) ? lds[tid - off] : 0;
        __syncthreads();
        lds[tid] += t;
        __syncthreads();
    }
    int ex = lds[tid] - s + bsum[blockIdx.x];
#pragma unroll
    for (int j = 0; j < 16; j++) {
        int i = base + j;
        if (i < n) { offs[i] = ex; cursor[i] = ex; ex += v[j]; }
    }
}

// ===========================================================================
// Bucket fill: group g = blockIdx % G writes only into its contiguous srcs
// region (group-major layout) -> XCD-local lines, 8x less cursor contention.
// ===========================================================================
__global__ __launch_bounds__(256)
void fill_kernel(const int* __restrict__ src, const int* __restrict__ dst,
                 int* __restrict__ cursor, int* __restrict__ srcs_sorted,
                 int n_edges, int n_nodes, int G) {
    int t = blockIdx.x * 256 + threadIdx.x;
    if (t >= n_edges) return;
    int g = blockIdx.x % G;
    int d = dst[t];
    int pos = atomicAdd(&cursor[(size_t)g * n_nodes + d], 1);
    srcs_sorted[pos] = src[t];
}

// ===========================================================================
// GEMM: H[n_rows x 64] = X[n_rows x K] @ W[K x 64]; output packed bf16.
// 64 rows x 64 cols per block, 256 threads, 4x4 register tile per thread.
// ===========================================================================
template <int K>
__global__ __launch_bounds__(256)
void gemm64_kernel(const float* __restrict__ X, const float* __restrict__ W,
                   unsigned short* __restrict__ H, int n_rows) {
    __shared__ float Xs[64][K + 4];
    __shared__ float Ws[K][64];

    const int tid  = threadIdx.x;
    const int row0 = blockIdx.x * 64;

    constexpr int WN4 = K * 64 / 4;
    const float4* W4 = (const float4*)W;
    float4* Ws4 = (float4*)&Ws[0][0];
    for (int i = tid; i < WN4; i += 256) Ws4[i] = W4[i];

    constexpr int KQ = K / 4;
    for (int i = tid; i < 64 * KQ; i += 256) {
        int r  = i / KQ;
        int k4 = i % KQ;
        int row = row0 + r;
        float4 v = make_float4(0.f, 0.f, 0.f, 0.f);
        if (row < n_rows) v = ((const float4*)(X + (size_t)row * K))[k4];
        *(float4*)&Xs[r][k4 * 4] = v;
    }
    __syncthreads();

    const int cg = (tid & 15) * 4;
    const int rg = (tid >> 4) * 4;

    float4 acc0 = make_float4(0.f,0.f,0.f,0.f);
    float4 acc1 = make_float4(0.f,0.f,0.f,0.f);
    float4 acc2 = make_float4(0.f,0.f,0.f,0.f);
    float4 acc3 = make_float4(0.f,0.f,0.f,0.f);

#pragma unroll 8
    for (int k = 0; k < K; k++) {
        float4 w = *(const float4*)&Ws[k][cg];
        float x0 = Xs[rg + 0][k];
        float x1 = Xs[rg + 1][k];
        float x2 = Xs[rg + 2][k];
        float x3 = Xs[rg + 3][k];
        acc0.x += x0 * w.x; acc0.y += x0 * w.y; acc0.z += x0 * w.z; acc0.w += x0 * w.w;
        acc1.x += x1 * w.x; acc1.y += x1 * w.y; acc1.z += x1 * w.z; acc1.w += x1 * w.w;
        acc2.x += x2 * w.x; acc2.y += x2 * w.y; acc2.z += x2 * w.z; acc2.w += x2 * w.w;
        acc3.x += x3 * w.x; acc3.y += x3 * w.y; acc3.z += x3 * w.z; acc3.w += x3 * w.w;
    }

    float4 accs[4] = {acc0, acc1, acc2, acc3};
#pragma unroll
    for (int i = 0; i < 4; i++) {
        int row = row0 + rg + i;
        if (row < n_rows) {
            ushort4 o = make_ushort4(f2bf(accs[i].x), f2bf(accs[i].y),
                                     f2bf(accs[i].z), f2bf(accs[i].w));
            *(ushort4*)(H + (size_t)row * 64 + cg) = o;
        }
    }
}

// ===========================================================================
// Segmented CSR gather (G segments per node, G templated for full unroll),
// bf16 h table, fused self-loop + bias + relu, fp32 output.
// 16 lanes per node, 4 channels each. Segment bounds hoisted (MLP), edge
// loop unrolled x2 so the two h-row loads issue concurrently.
// ===========================================================================
template <int G>
__global__ __launch_bounds__(256)
void gather_agg_kernel(const int* __restrict__ offs, const int* __restrict__ srcs_sorted,
                       const float* __restrict__ dinv, const unsigned short* __restrict__ h,
                       const float* __restrict__ b, float* __restrict__ out,
                       int n_nodes) {
    int t = blockIdx.x * blockDim.x + threadIdx.x;
    int node = t >> 4;
    if (node >= n_nodes) return;
    int cg = (t & 15) * 4;

    float dn = dinv[node];

    // hoist all segment bounds (issued together; static indexing)
    int i0s[G], i1s[G];
#pragma unroll
    for (int g = 0; g < G; g++) {
        i0s[g] = offs[(size_t)g * n_nodes + node];
        i1s[g] = offs[(size_t)g * n_nodes + node + 1];
    }

    float4 acc;
    {
        float c2 = dn * dn;
        ushort4 hu = *(const ushort4*)(h + (size_t)node * 64 + cg);
        acc.x = bf2f(hu.x) * c2; acc.y = bf2f(hu.y) * c2;
        acc.z = bf2f(hu.z) * c2; acc.w = bf2f(hu.w) * c2;
    }

#pragma unroll
    for (int g = 0; g < G; g++) {
        int i = i0s[g];
        int i1 = i1s[g];
        for (; i + 2 <= i1; i += 2) {
            int s0 = srcs_sorted[i];
            int s1 = srcs_sorted[i + 1];
            float c0 = dinv[s0] * dn;
            float c1 = dinv[s1] * dn;
            ushort4 u0 = *(const ushort4*)(h + (size_t)s0 * 64 + cg);
            ushort4 u1 = *(const ushort4*)(h + (size_t)s1 * 64 + cg);
            acc.x += bf2f(u0.x) * c0 + bf2f(u1.x) * c1;
            acc.y += bf2f(u0.y) * c0 + bf2f(u1.y) * c1;
            acc.z += bf2f(u0.z) * c0 + bf2f(u1.z) * c1;
            acc.w += bf2f(u0.w) * c0 + bf2f(u1.w) * c1;
        }
        if (i < i1) {
            int s0 = srcs_sorted[i];
            float c0 = dinv[s0] * dn;
            ushort4 u0 = *(const ushort4*)(h + (size_t)s0 * 64 + cg);
            acc.x += bf2f(u0.x) * c0;
            acc.y += bf2f(u0.y) * c0;
            acc.z += bf2f(u0.z) * c0;
            acc.w += bf2f(u0.w) * c0;
        }
    }

    float4 bv = *(const float4*)(b + cg);
    float4 r;
    r.x = fmaxf(acc.x + bv.x, 0.f);
    r.y = fmaxf(acc.y + bv.y, 0.f);
    r.z = fmaxf(acc.z + bv.z, 0.f);
    r.w = fmaxf(acc.w + bv.w, 0.f);
    *(float4*)(out + (size_t)node * 64 + cg) = r;
}

// ===========================================================================
// Pooling (batch sorted): one wave per chunk of nodes; lane = channel.
// chunk=32 -> 3125 waves so the 256-CU chip is actually occupied.
// ===========================================================================
__global__ __launch_bounds__(256)
void pool_kernel(const float* __restrict__ h, const int* __restrict__ batch,
                 float* __restrict__ pooled, float* __restrict__ cnt,
                 int n_nodes, int chunk) {
    int wave = (blockIdx.x * blockDim.x + threadIdx.x) >> 6;
    int lane = threadIdx.x & 63;
    int start = wave * chunk;
    if (start >= n_nodes) return;
    int end = min(start + chunk, n_nodes);

    int cur = batch[start];
    float acc = 0.f;
    float c = 0.f;
    for (int i = start; i < end; i++) {
        int g = batch[i];
        if (g != cur) {
            unsafeAtomicAdd(&pooled[(size_t)cur * 64 + lane], acc);
            if (lane == 0) unsafeAtomicAdd(&cnt[cur], c);
            acc = 0.f; c = 0.f; cur = g;
        }
        acc += h[(size_t)i * 64 + lane];
        c += 1.f;
    }
    unsafeAtomicAdd(&pooled[(size_t)cur * 64 + lane], acc);
    if (lane == 0) unsafeAtomicAdd(&cnt[cur], c);
}

__global__ __launch_bounds__(256)
void head_kernel(const float* __restrict__ pooled, const float* __restrict__ cnt,
                 const float* __restrict__ Wfc, const float* __restrict__ bfc,
                 float* __restrict__ out) {
    __shared__ float Ws[HIDDEN * N_CLASSES];
    __shared__ float bs[N_CLASSES];
    int tid = threadIdx.x;
    for (int i = tid; i < HIDDEN * N_CLASSES; i += 256) Ws[i] = Wfc[i];
    if (tid < N_CLASSES) bs[tid] = bfc[tid];
    __syncthreads();

    int g = blockIdx.x * 256 + tid;
    if (g >= N_GRAPHS) return;

    float inv = 1.f / fmaxf(cnt[g], 1.f);
    float p[HIDDEN];
#pragma unroll
    for (int k = 0; k < HIDDEN; k++) p[k] = pooled[(size_t)g * 64 + k] * inv;

    float lg[N_CLASSES];
    float m = -1e30f;
#pragma unroll
    for (int j = 0; j < N_CLASSES; j++) {
        float a = bs[j];
#pragma unroll
        for (int k = 0; k < HIDDEN; k++) a += p[k] * Ws[k * N_CLASSES + j];
        lg[j] = a;
        m = fmaxf(m, a);
    }
    float s = 0.f;
#pragma unroll
    for (int j = 0; j < N_CLASSES; j++) s += __expf(lg[j] - m);
    float lse = m + __logf(s);
#pragma unroll
    for (int j = 0; j < N_CLASSES; j++) out[(size_t)g * N_CLASSES + j] = lg[j] - lse;
}

// ===========================================================================
// Launch
// ===========================================================================
extern "C" void kernel_launch(void* const* d_in, const int* in_sizes, int n_in,
                              void* d_out, int out_size, void* d_ws, size_t ws_size,
                              hipStream_t stream) {
    const float* x   = (const float*)d_in[0];
    const int*   ei  = (const int*)d_in[1];
    const int*   bat = (const int*)d_in[2];
    const float* W1  = (const float*)d_in[3];
    const float* b1  = (const float*)d_in[4];
    const float* W2  = (const float*)d_in[5];
    const float* b2  = (const float*)d_in[6];
    const float* Wfc = (const float*)d_in[7];
    const float* bfc = (const float*)d_in[8];
    float* out = (float*)d_out;

    const int* src = ei;
    const int* dst = ei + N_EDGES;

    char* ws = (char*)d_ws;

    // NEEDED(G) = 58,135,184 + 800,000*G   (layout below; proven at G=8 in R3/R4)
    int G;
    if      (ws_size >= 58135184 + 800000 * (size_t)8) G = 8;
    else if (ws_size >= 58135184 + 800000 * (size_t)2) G = 2;
    else                                               G = 1;

    const size_t OFF_BUFA = 0;                                   // bf16 h table (12.8 MB used)
    const size_t OFF_BUFB = 25600000;                            // 25,600,000 fp32
    const size_t OFF_DINV = 51200000;                            //    400,000
    const size_t OFF_OFFS = 51600000;                            // G*400,000 + 16
    const size_t OFF_CURS = OFF_OFFS + (size_t)G * 400000 + 16;  // G*400,000  (also degi)
    const size_t OFF_BSUM = OFF_CURS + (size_t)G * 400000;       //      2,048
    const size_t OFF_POOL = OFF_BSUM + 2048;                     //    131,072
    const size_t OFF_CNT  = OFF_POOL + 131072;                   //      2,048
    const size_t OFF_SRCS = OFF_CNT + 2048;                      //  6,400,000

    unsigned short* bufA = (unsigned short*)(ws + OFF_BUFA);     // bf16 h
    float* bufB   = (float*)(ws + OFF_BUFB);
    float* dinv   = (float*)(ws + OFF_DINV);
    int*   offs   = (int*)  (ws + OFF_OFFS);
    int*   degi   = (int*)  (ws + OFF_CURS);   // histogram, then cursor
    int*   bsum   = (int*)  (ws + OFF_BSUM);
    float* pooled = (float*)(ws + OFF_POOL);
    float* cnt    = (float*)(ws + OFF_CNT);
    int*   srcs   = (int*)  (ws + OFF_SRCS);

    const int GN = G * N_NODES;
    const int SCAN_BLOCKS = (GN + 4095) / 4096;     // G=8 -> 196 (<=256 ok)
    const int EDGE_BLOCKS = (N_EDGES + 255) / 256;  // 6250
    const int GATHER_BLOCKS = (N_NODES * 16 + 255) / 256;

    // --- build group-split CSR (reused by both layers) ---
    hipMemsetAsync(degi, 0, (size_t)GN * sizeof(int), stream);
    hist_kernel<<<EDGE_BLOCKS, 256, 0, stream>>>(dst, degi, N_EDGES, N_NODES, G);
    dinv_sum_kernel<<<(N_NODES + 255) / 256, 256, 0, stream>>>(degi, dinv, N_NODES, G);
    scan1_kernel<<<SCAN_BLOCKS, 256, 0, stream>>>(degi, bsum, GN);
    scan2_kernel<<<1, 256, 0, stream>>>(bsum, offs, SCAN_BLOCKS, GN);
    scan3_kernel<<<SCAN_BLOCKS, 256, 0, stream>>>(degi, bsum, offs, degi, GN);
    fill_kernel<<<EDGE_BLOCKS, 256, 0, stream>>>(src, dst, degi, srcs, N_EDGES, N_NODES, G);

    // --- layer 1 ---
    gemm64_kernel<D_IN><<<(N_NODES + 63) / 64, 256, 0, stream>>>(x, W1, bufA, N_NODES);
    if (G == 8)      gather_agg_kernel<8><<<GATHER_BLOCKS, 256, 0, stream>>>(offs, srcs, dinv, bufA, b1, bufB, N_NODES);
    else if (G == 2) gather_agg_kernel<2><<<GATHER_BLOCKS, 256, 0, stream>>>(offs, srcs, dinv, bufA, b1, bufB, N_NODES);
    else             gather_agg_kernel<1><<<GATHER_BLOCKS, 256, 0, stream>>>(offs, srcs, dinv, bufA, b1, bufB, N_NODES);

    // --- layer 2 ---
    gemm64_kernel<HIDDEN><<<(N_NODES + 63) / 64, 256, 0, stream>>>(bufB, W2, bufA, N_NODES);
    if (G == 8)      gather_agg_kernel<8><<<GATHER_BLOCKS, 256, 0, stream>>>(offs, srcs, dinv, bufA, b2, bufB, N_NODES);
    else if (G == 2) gather_agg_kernel<2><<<GATHER_BLOCKS, 256, 0, stream>>>(offs, srcs, dinv, bufA, b2, bufB, N_NODES);
    else             gather_agg_kernel<1><<<GATHER_BLOCKS, 256, 0, stream>>>(offs, srcs, dinv, bufA, b2, bufB, N_NODES);

    // --- pooling + head ---
    hipMemsetAsync(pooled, 0, (size_t)N_GRAPHS * 64 * sizeof(float), stream);
    hipMemsetAsync(cnt, 0, (size_t)N_GRAPHS * sizeof(float), stream);
    {
        const int chunk = 32;   // 3125 waves -> ~12 waves/CU
        int waves  = (N_NODES + chunk - 1) / chunk;
        int blocks = (waves + 3) / 4;
        pool_kernel<<<blocks, 256, 0, stream>>>(bufB, bat, pooled, cnt, N_NODES, chunk);
    }
    head_kernel<<<(N_GRAPHS + 255) / 256, 256, 0, stream>>>(pooled, cnt, Wfc, bfc, out);
}

// Round 6
// 376.844 us; speedup vs baseline: 1.5709x; 1.2688x over previous
//
#include <hip/hip_runtime.h>
#include <cstdint>
#include <cstddef>

#define N_NODES   100000
#define N_EDGES   1600000
#define D_IN      128
#define HIDDEN    64
#define N_GRAPHS  512
#define N_CLASSES 10

// ---- bf16 helpers (RNE pack, bit-shift unpack) ----
__device__ inline float bf2f(unsigned short u) {
    return __uint_as_float(((unsigned int)u) << 16);
}
__device__ inline unsigned short f2bf(float f) {
    unsigned int x = __float_as_uint(f);
    return (unsigned short)((x + 0x7FFF + ((x >> 16) & 1)) >> 16);
}

// ===========================================================================
// Histogram + rank: group g = blockIdx % G counts into its own copy; the
// atomic's return value is the edge's within-bucket rank (makes fill atomic-free).
// ===========================================================================
__global__ __launch_bounds__(256)
void hist_rank_kernel(const int* __restrict__ dst, int* __restrict__ degi,
                      int* __restrict__ rank, int n_edges, int n_nodes, int G) {
    int t = blockIdx.x * 256 + threadIdx.x;
    if (t >= n_edges) return;
    int g = blockIdx.x % G;
    int r = atomicAdd(&degi[(size_t)g * n_nodes + dst[t]], 1);
    rank[t] = r;
}

// dinv[n] = rsqrt(sum_g degi[g][n] + 1); degsum[n] = sum (for node-major scan)
__global__ void dinv_sum_kernel(const int* __restrict__ degi, float* __restrict__ dinv,
                                int* __restrict__ degsum, int n_nodes, int G) {
    int t = blockIdx.x * blockDim.x + threadIdx.x;
    if (t >= n_nodes) return;
    int s = 0;
    for (int g = 0; g < G; g++) s += degi[(size_t)g * n_nodes + t];
    dinv[t] = rsqrtf((float)s + 1.0f);
    degsum[t] = s;
}

// ===========================================================================
// Exclusive prefix scan (generic, int): 4096 elems per 256-thread block.
// ===========================================================================
__global__ __launch_bounds__(256)
void scan1_kernel(const int* __restrict__ in, int* __restrict__ bsum, int n) {
    __shared__ int lds[256];
    int tid = threadIdx.x;
    int base = blockIdx.x * 4096 + tid * 16;
    int s = 0;
#pragma unroll
    for (int j = 0; j < 16; j++) { int i = base + j; if (i < n) s += in[i]; }
    lds[tid] = s; __syncthreads();
    for (int off = 128; off > 0; off >>= 1) {
        if (tid < off) lds[tid] += lds[tid + off];
        __syncthreads();
    }
    if (tid == 0) bsum[blockIdx.x] = lds[0];
}

__global__ __launch_bounds__(256)
void scan2_kernel(int* __restrict__ bsum, int* __restrict__ out, int nb, int n) {
    __shared__ int lds[256];
    int tid = threadIdx.x;
    int v = (tid < nb) ? bsum[tid] : 0;
    lds[tid] = v; __syncthreads();
    for (int off = 1; off < 256; off <<= 1) {
        int t = (tid >= off) ? lds[tid - off] : 0;
        __syncthreads();
        lds[tid] += t;
        __syncthreads();
    }
    if (tid < nb) bsum[tid] = lds[tid] - v;   // exclusive block offsets
    if (tid == 255) out[n] = lds[255];        // grand total
}

__global__ __launch_bounds__(256)
void scan3_kernel(const int* __restrict__ in, const int* __restrict__ bsum,
                  int* __restrict__ out, int n) {
    __shared__ int lds[256];
    int tid = threadIdx.x;
    int base = blockIdx.x * 4096 + tid * 16;
    int v[16]; int s = 0;
#pragma unroll
    for (int j = 0; j < 16; j++) {
        int i = base + j;
        v[j] = (i < n) ? in[i] : 0;
        s += v[j];
    }
    lds[tid] = s; __syncthreads();
    for (int off = 1; off < 256; off <<= 1) {
        int t = (tid >= off) ? lds[tid - off] : 0;
        __syncthreads();
        lds[tid] += t;
        __syncthreads();
    }
    int ex = lds[tid] - s + bsum[blockIdx.x];
#pragma unroll
    for (int j = 0; j < 16; j++) {
        int i = base + j;
        if (i < n) { out[i] = ex; ex += v[j]; }
    }
}

// ===========================================================================
// Atomic-free bucket fill: pos = offs_gm[g][dst] + rank[e] (group-major,
// XCD-local write regions).
// ===========================================================================
__global__ __launch_bounds__(256)
void fill2_kernel(const int* __restrict__ src, const int* __restrict__ dst,
                  const int* __restrict__ offs_gm, const int* __restrict__ rank,
                  int* __restrict__ srcs_gm, int n_edges, int n_nodes, int G) {
    int t = blockIdx.x * 256 + threadIdx.x;
    if (t >= n_edges) return;
    int g = blockIdx.x % G;
    int d = dst[t];
    int pos = offs_gm[(size_t)g * n_nodes + d] + rank[t];
    srcs_gm[pos] = src[t];
}

// ===========================================================================
// Reorder group-major srcs -> node-major srcs2 (one contiguous segment/node).
// One thread per node; sequential writes, random-ish segment reads.
// ===========================================================================
__global__ __launch_bounds__(256)
void reorder_kernel(const int* __restrict__ offs_gm, const int* __restrict__ srcs_gm,
                    const int* __restrict__ node_offs, int* __restrict__ srcs2,
                    int n_nodes, int G) {
    int n = blockIdx.x * 256 + threadIdx.x;
    if (n >= n_nodes) return;
    int base = node_offs[n];
    for (int g = 0; g < G; g++) {
        int a = offs_gm[(size_t)g * n_nodes + n];
        int e = offs_gm[(size_t)g * n_nodes + n + 1];
        for (int i = a; i < e; i++) srcs2[base++] = srcs_gm[i];
    }
}

// ===========================================================================
// GEMM: H[n_rows x 64] = X[n_rows x K] @ W[K x 64]; output packed bf16.
// ===========================================================================
template <int K>
__global__ __launch_bounds__(256)
void gemm64_kernel(const float* __restrict__ X, const float* __restrict__ W,
                   unsigned short* __restrict__ H, int n_rows) {
    __shared__ float Xs[64][K + 4];
    __shared__ float Ws[K][64];

    const int tid  = threadIdx.x;
    const int row0 = blockIdx.x * 64;

    constexpr int WN4 = K * 64 / 4;
    const float4* W4 = (const float4*)W;
    float4* Ws4 = (float4*)&Ws[0][0];
    for (int i = tid; i < WN4; i += 256) Ws4[i] = W4[i];

    constexpr int KQ = K / 4;
    for (int i = tid; i < 64 * KQ; i += 256) {
        int r  = i / KQ;
        int k4 = i % KQ;
        int row = row0 + r;
        float4 v = make_float4(0.f, 0.f, 0.f, 0.f);
        if (row < n_rows) v = ((const float4*)(X + (size_t)row * K))[k4];
        *(float4*)&Xs[r][k4 * 4] = v;
    }
    __syncthreads();

    const int cg = (tid & 15) * 4;
    const int rg = (tid >> 4) * 4;

    float4 acc0 = make_float4(0.f,0.f,0.f,0.f);
    float4 acc1 = make_float4(0.f,0.f,0.f,0.f);
    float4 acc2 = make_float4(0.f,0.f,0.f,0.f);
    float4 acc3 = make_float4(0.f,0.f,0.f,0.f);

#pragma unroll 8
    for (int k = 0; k < K; k++) {
        float4 w = *(const float4*)&Ws[k][cg];
        float x0 = Xs[rg + 0][k];
        float x1 = Xs[rg + 1][k];
        float x2 = Xs[rg + 2][k];
        float x3 = Xs[rg + 3][k];
        acc0.x += x0 * w.x; acc0.y += x0 * w.y; acc0.z += x0 * w.z; acc0.w += x0 * w.w;
        acc1.x += x1 * w.x; acc1.y += x1 * w.y; acc1.z += x1 * w.z; acc1.w += x1 * w.w;
        acc2.x += x2 * w.x; acc2.y += x2 * w.y; acc2.z += x2 * w.z; acc2.w += x2 * w.w;
        acc3.x += x3 * w.x; acc3.y += x3 * w.y; acc3.z += x3 * w.z; acc3.w += x3 * w.w;
    }

    float4 accs[4] = {acc0, acc1, acc2, acc3};
#pragma unroll
    for (int i = 0; i < 4; i++) {
        int row = row0 + rg + i;
        if (row < n_rows) {
            ushort4 o = make_ushort4(f2bf(accs[i].x), f2bf(accs[i].y),
                                     f2bf(accs[i].z), f2bf(accs[i].w));
            *(ushort4*)(H + (size_t)row * 64 + cg) = o;
        }
    }
}

// ===========================================================================
// Flat CSR gather: 8 lanes/node, 8 channels/lane (int4 = 8 bf16 per load),
// edge loop unrolled x4 -> up to 4 outstanding h-row loads per chain,
// 8 chains per wave. Fused self-loop + bias + relu, fp32 out.
// ===========================================================================
__device__ inline void upk_fma(int4 u, float c, float* acc) {
    unsigned int a = (unsigned int)u.x, b = (unsigned int)u.y;
    unsigned int d = (unsigned int)u.z, e = (unsigned int)u.w;
    acc[0] += __uint_as_float(a << 16) * c;
    acc[1] += __uint_as_float(a & 0xFFFF0000u) * c;
    acc[2] += __uint_as_float(b << 16) * c;
    acc[3] += __uint_as_float(b & 0xFFFF0000u) * c;
    acc[4] += __uint_as_float(d << 16) * c;
    acc[5] += __uint_as_float(d & 0xFFFF0000u) * c;
    acc[6] += __uint_as_float(e << 16) * c;
    acc[7] += __uint_as_float(e & 0xFFFF0000u) * c;
}

__global__ __launch_bounds__(256)
void gather_flat_kernel(const int* __restrict__ offs, const int* __restrict__ srcs,
                        const float* __restrict__ dinv, const unsigned short* __restrict__ h,
                        const float* __restrict__ b, float* __restrict__ out, int n_nodes) {
    int t = blockIdx.x * 256 + threadIdx.x;
    int node = t >> 3;
    if (node >= n_nodes) return;
    int cg = (t & 7) * 8;   // channel offset (ushorts)

    float dn = dinv[node];
    float acc[8];
    {
        int4 u = *(const int4*)(h + (size_t)node * 64 + cg);
        float c2 = dn * dn;
        unsigned int a = (unsigned int)u.x, bb = (unsigned int)u.y;
        unsigned int d = (unsigned int)u.z, e = (unsigned int)u.w;
        acc[0] = __uint_as_float(a << 16) * c2;
        acc[1] = __uint_as_float(a & 0xFFFF0000u) * c2;
        acc[2] = __uint_as_float(bb << 16) * c2;
        acc[3] = __uint_as_float(bb & 0xFFFF0000u) * c2;
        acc[4] = __uint_as_float(d << 16) * c2;
        acc[5] = __uint_as_float(d & 0xFFFF0000u) * c2;
        acc[6] = __uint_as_float(e << 16) * c2;
        acc[7] = __uint_as_float(e & 0xFFFF0000u) * c2;
    }

    int i  = offs[node];
    int i1 = offs[node + 1];
    for (; i + 4 <= i1; i += 4) {
        int s0 = srcs[i];
        int s1 = srcs[i + 1];
        int s2 = srcs[i + 2];
        int s3 = srcs[i + 3];
        float c0 = dinv[s0] * dn;
        float c1 = dinv[s1] * dn;
        float c2 = dinv[s2] * dn;
        float c3 = dinv[s3] * dn;
        int4 u0 = *(const int4*)(h + (size_t)s0 * 64 + cg);
        int4 u1 = *(const int4*)(h + (size_t)s1 * 64 + cg);
        int4 u2 = *(const int4*)(h + (size_t)s2 * 64 + cg);
        int4 u3 = *(const int4*)(h + (size_t)s3 * 64 + cg);
        upk_fma(u0, c0, acc);
        upk_fma(u1, c1, acc);
        upk_fma(u2, c2, acc);
        upk_fma(u3, c3, acc);
    }
    for (; i < i1; i++) {
        int s0 = srcs[i];
        float c0 = dinv[s0] * dn;
        int4 u0 = *(const int4*)(h + (size_t)s0 * 64 + cg);
        upk_fma(u0, c0, acc);
    }

    float4 b0 = *(const float4*)(b + cg);
    float4 b1 = *(const float4*)(b + cg + 4);
    float* o = out + (size_t)node * 64 + cg;
    float4 r0, r1;
    r0.x = fmaxf(acc[0] + b0.x, 0.f);
    r0.y = fmaxf(acc[1] + b0.y, 0.f);
    r0.z = fmaxf(acc[2] + b0.z, 0.f);
    r0.w = fmaxf(acc[3] + b0.w, 0.f);
    r1.x = fmaxf(acc[4] + b1.x, 0.f);
    r1.y = fmaxf(acc[5] + b1.y, 0.f);
    r1.z = fmaxf(acc[6] + b1.z, 0.f);
    r1.w = fmaxf(acc[7] + b1.w, 0.f);
    *(float4*)(o)     = r0;
    *(float4*)(o + 4) = r1;
}

// ===========================================================================
// Pooling (batch sorted): one wave per 32-node chunk; lane = channel.
// ===========================================================================
__global__ __launch_bounds__(256)
void pool_kernel(const float* __restrict__ h, const int* __restrict__ batch,
                 float* __restrict__ pooled, float* __restrict__ cnt,
                 int n_nodes, int chunk) {
    int wave = (blockIdx.x * blockDim.x + threadIdx.x) >> 6;
    int lane = threadIdx.x & 63;
    int start = wave * chunk;
    if (start >= n_nodes) return;
    int end = min(start + chunk, n_nodes);

    int cur = batch[start];
    float acc = 0.f;
    float c = 0.f;
    for (int i = start; i < end; i++) {
        int g = batch[i];
        if (g != cur) {
            unsafeAtomicAdd(&pooled[(size_t)cur * 64 + lane], acc);
            if (lane == 0) unsafeAtomicAdd(&cnt[cur], c);
            acc = 0.f; c = 0.f; cur = g;
        }
        acc += h[(size_t)i * 64 + lane];
        c += 1.f;
    }
    unsafeAtomicAdd(&pooled[(size_t)cur * 64 + lane], acc);
    if (lane == 0) unsafeAtomicAdd(&cnt[cur], c);
}

__global__ __launch_bounds__(256)
void head_kernel(const float* __restrict__ pooled, const float* __restrict__ cnt,
                 const float* __restrict__ Wfc, const float* __restrict__ bfc,
                 float* __restrict__ out) {
    __shared__ float Ws[HIDDEN * N_CLASSES];
    __shared__ float bs[N_CLASSES];
    int tid = threadIdx.x;
    for (int i = tid; i < HIDDEN * N_CLASSES; i += 256) Ws[i] = Wfc[i];
    if (tid < N_CLASSES) bs[tid] = bfc[tid];
    __syncthreads();

    int g = blockIdx.x * 256 + tid;
    if (g >= N_GRAPHS) return;

    float inv = 1.f / fmaxf(cnt[g], 1.f);
    float p[HIDDEN];
#pragma unroll
    for (int k = 0; k < HIDDEN; k++) p[k] = pooled[(size_t)g * 64 + k] * inv;

    float lg[N_CLASSES];
    float m = -1e30f;
#pragma unroll
    for (int j = 0; j < N_CLASSES; j++) {
        float a = bs[j];
#pragma unroll
        for (int k = 0; k < HIDDEN; k++) a += p[k] * Ws[k * N_CLASSES + j];
        lg[j] = a;
        m = fmaxf(m, a);
    }
    float s = 0.f;
#pragma unroll
    for (int j = 0; j < N_CLASSES; j++) s += __expf(lg[j] - m);
    float lse = m + __logf(s);
#pragma unroll
    for (int j = 0; j < N_CLASSES; j++) out[(size_t)g * N_CLASSES + j] = lg[j] - lse;
}

// ===========================================================================
// Launch
// ===========================================================================
extern "C" void kernel_launch(void* const* d_in, const int* in_sizes, int n_in,
                              void* d_out, int out_size, void* d_ws, size_t ws_size,
                              hipStream_t stream) {
    const float* x   = (const float*)d_in[0];
    const int*   ei  = (const int*)d_in[1];
    const int*   bat = (const int*)d_in[2];
    const float* W1  = (const float*)d_in[3];
    const float* b1  = (const float*)d_in[4];
    const float* W2  = (const float*)d_in[5];
    const float* b2  = (const float*)d_in[6];
    const float* Wfc = (const float*)d_in[7];
    const float* bfc = (const float*)d_in[8];
    float* out = (float*)d_out;

    const int* src = ei;
    const int* dst = ei + N_EDGES;

    char* ws = (char*)d_ws;

    // NEEDED(G) = 58,135,184 + 800,000*G   (unchanged from R3-R5; G=8 proven)
    int G;
    if      (ws_size >= 58135184 + 800000 * (size_t)8) G = 8;
    else if (ws_size >= 58135184 + 800000 * (size_t)2) G = 2;
    else                                               G = 1;

    // Main layout (same footprint as R3-R5):
    const size_t OFF_BUFA = 0;                                   // 25.6 MB region (see sub-layout)
    const size_t OFF_BUFB = 25600000;                            // 25.6 MB fp32 (rank[] during build)
    const size_t OFF_DINV = 51200000;                            //    400,000
    const size_t OFF_OFFS = 51600000;                            // G*400,000 + 16
    const size_t OFF_CURS = OFF_OFFS + (size_t)G * 400000 + 16;  // G*400,000 (degi)
    const size_t OFF_BSUM = OFF_CURS + (size_t)G * 400000;       //      2,048
    const size_t OFF_POOL = OFF_BSUM + 2048;                     //    131,072
    const size_t OFF_CNT  = OFF_POOL + 131072;                   //      2,048
    const size_t OFF_SRCS = OFF_CNT + 2048;                      //  6,400,000 (group-major)

    // Sub-layout inside bufA region (gemm writes only [0, 12.8 MB)):
    const size_t OFF_H     = OFF_BUFA;                // 12,800,000 bf16 h table
    const size_t OFF_SRCS2 = OFF_BUFA + 12800000;     //  6,400,000 node-major srcs
    const size_t OFF_NOFFS = OFF_BUFA + 19200000;     //    400,016 node offs (N+1)
    const size_t OFF_DEGS  = OFF_BUFA + 19600016;     //    400,000 degsum

    unsigned short* bufA = (unsigned short*)(ws + OFF_H);
    int*   srcs2  = (int*)  (ws + OFF_SRCS2);
    int*   noffs  = (int*)  (ws + OFF_NOFFS);
    int*   degsum = (int*)  (ws + OFF_DEGS);
    float* bufB   = (float*)(ws + OFF_BUFB);
    int*   rank   = (int*)  (ws + OFF_BUFB);   // aliases bufB during CSR build only
    float* dinv   = (float*)(ws + OFF_DINV);
    int*   offs   = (int*)  (ws + OFF_OFFS);   // group-major offsets
    int*   degi   = (int*)  (ws + OFF_CURS);
    int*   bsum   = (int*)  (ws + OFF_BSUM);
    float* pooled = (float*)(ws + OFF_POOL);
    float* cnt    = (float*)(ws + OFF_CNT);
    int*   srcs   = (int*)  (ws + OFF_SRCS);   // group-major srcs

    const int GN = G * N_NODES;
    const int SCAN_BLOCKS_GN = (GN + 4095) / 4096;       // G=8 -> 196
    const int SCAN_BLOCKS_N  = (N_NODES + 4095) / 4096;  // 25
    const int EDGE_BLOCKS = (N_EDGES + 255) / 256;       // 6250
    const int NODE_BLOCKS = (N_NODES + 255) / 256;
    const int GATHER_BLOCKS = (N_NODES * 8 + 255) / 256; // 3125

    // --- build CSR (group-major fill, then node-major reorder) ---
    hipMemsetAsync(degi, 0, (size_t)GN * sizeof(int), stream);
    hist_rank_kernel<<<EDGE_BLOCKS, 256, 0, stream>>>(dst, degi, rank, N_EDGES, N_NODES, G);
    dinv_sum_kernel<<<NODE_BLOCKS, 256, 0, stream>>>(degi, dinv, degsum, N_NODES, G);
    // group-major scan
    scan1_kernel<<<SCAN_BLOCKS_GN, 256, 0, stream>>>(degi, bsum, GN);
    scan2_kernel<<<1, 256, 0, stream>>>(bsum, offs, SCAN_BLOCKS_GN, GN);
    scan3_kernel<<<SCAN_BLOCKS_GN, 256, 0, stream>>>(degi, bsum, offs, GN);
    // node-major scan
    scan1_kernel<<<SCAN_BLOCKS_N, 256, 0, stream>>>(degsum, bsum, N_NODES);
    scan2_kernel<<<1, 256, 0, stream>>>(bsum, noffs, SCAN_BLOCKS_N, N_NODES);
    scan3_kernel<<<SCAN_BLOCKS_N, 256, 0, stream>>>(degsum, bsum, noffs, N_NODES);
    // atomic-free fill + reorder
    fill2_kernel<<<EDGE_BLOCKS, 256, 0, stream>>>(src, dst, offs, rank, srcs, N_EDGES, N_NODES, G);
    reorder_kernel<<<NODE_BLOCKS, 256, 0, stream>>>(offs, srcs, noffs, srcs2, N_NODES, G);

    // --- layer 1 ---
    gemm64_kernel<D_IN><<<(N_NODES + 63) / 64, 256, 0, stream>>>(x, W1, bufA, N_NODES);
    gather_flat_kernel<<<GATHER_BLOCKS, 256, 0, stream>>>(noffs, srcs2, dinv, bufA, b1, bufB, N_NODES);

    // --- layer 2 ---
    gemm64_kernel<HIDDEN><<<(N_NODES + 63) / 64, 256, 0, stream>>>(bufB, W2, bufA, N_NODES);
    gather_flat_kernel<<<GATHER_BLOCKS, 256, 0, stream>>>(noffs, srcs2, dinv, bufA, b2, bufB, N_NODES);

    // --- pooling + head ---
    hipMemsetAsync(pooled, 0, (size_t)N_GRAPHS * 64 * sizeof(float), stream);
    hipMemsetAsync(cnt, 0, (size_t)N_GRAPHS * sizeof(float), stream);
    {
        const int chunk = 32;
        int waves  = (N_NODES + chunk - 1) / chunk;
        int blocks = (waves + 3) / 4;
        pool_kernel<<<blocks, 256, 0, stream>>>(bufB, bat, pooled, cnt, N_NODES, chunk);
    }
    head_kernel<<<(N_GRAPHS + 255) / 256, 256, 0, stream>>>(pooled, cnt, Wfc, bfc, out);
}

// Round 7
// 346.424 us; speedup vs baseline: 1.7089x; 1.0878x over previous
//
#include <hip/hip_runtime.h>
#include <cstdint>
#include <cstddef>

#define N_NODES   100000
#define N_EDGES   1600000
#define D_IN      128
#define HIDDEN    64
#define N_GRAPHS  512
#define N_CLASSES 10

typedef __attribute__((ext_vector_type(8))) short bf16x8;
typedef __attribute__((ext_vector_type(4))) float f32x4;

// ---- bf16 helpers (RNE pack, bit-shift unpack) ----
__device__ inline float bf2f(unsigned short u) {
    return __uint_as_float(((unsigned int)u) << 16);
}
__device__ inline unsigned short f2bf(float f) {
    unsigned int x = __float_as_uint(f);
    return (unsigned short)((x + 0x7FFF + ((x >> 16) & 1)) >> 16);
}

// ===========================================================================
// Histogram + rank, 4 edges per thread (4 returning atomics in flight/lane).
// Bucket mapping g = blockIdx % G must match fill2 exactly.
// ===========================================================================
__global__ __launch_bounds__(256)
void hist_rank_kernel(const int* __restrict__ dst, int* __restrict__ degi,
                      int* __restrict__ rank, int n_edges, int n_nodes, int G) {
    int base = blockIdx.x * 1024 + threadIdx.x;
    int g = blockIdx.x % G;
    int* dg = degi + (size_t)g * n_nodes;
#pragma unroll
    for (int j = 0; j < 4; j++) {
        int t = base + j * 256;
        if (t < n_edges) rank[t] = atomicAdd(&dg[dst[t]], 1);
    }
}

// dinv[n] = rsqrt(sum_g degi[g][n] + 1); degsum[n] = sum (for node-major scan)
__global__ void dinv_sum_kernel(const int* __restrict__ degi, float* __restrict__ dinv,
                                int* __restrict__ degsum, int n_nodes, int G) {
    int t = blockIdx.x * blockDim.x + threadIdx.x;
    if (t >= n_nodes) return;
    int s = 0;
    for (int g = 0; g < G; g++) s += degi[(size_t)g * n_nodes + t];
    dinv[t] = rsqrtf((float)s + 1.0f);
    degsum[t] = s;
}

// ===========================================================================
// Exclusive prefix scan (generic, int): 4096 elems per 256-thread block.
// ===========================================================================
__global__ __launch_bounds__(256)
void scan1_kernel(const int* __restrict__ in, int* __restrict__ bsum, int n) {
    __shared__ int lds[256];
    int tid = threadIdx.x;
    int base = blockIdx.x * 4096 + tid * 16;
    int s = 0;
#pragma unroll
    for (int j = 0; j < 16; j++) { int i = base + j; if (i < n) s += in[i]; }
    lds[tid] = s; __syncthreads();
    for (int off = 128; off > 0; off >>= 1) {
        if (tid < off) lds[tid] += lds[tid + off];
        __syncthreads();
    }
    if (tid == 0) bsum[blockIdx.x] = lds[0];
}

__global__ __launch_bounds__(256)
void scan2_kernel(int* __restrict__ bsum, int* __restrict__ out, int nb, int n) {
    __shared__ int lds[256];
    int tid = threadIdx.x;
    int v = (tid < nb) ? bsum[tid] : 0;
    lds[tid] = v; __syncthreads();
    for (int off = 1; off < 256; off <<= 1) {
        int t = (tid >= off) ? lds[tid - off] : 0;
        __syncthreads();
        lds[tid] += t;
        __syncthreads();
    }
    if (tid < nb) bsum[tid] = lds[tid] - v;   // exclusive block offsets
    if (tid == 255) out[n] = lds[255];        // grand total
}

__global__ __launch_bounds__(256)
void scan3_kernel(const int* __restrict__ in, const int* __restrict__ bsum,
                  int* __restrict__ out, int n) {
    __shared__ int lds[256];
    int tid = threadIdx.x;
    int base = blockIdx.x * 4096 + tid * 16;
    int v[16]; int s = 0;
#pragma unroll
    for (int j = 0; j < 16; j++) {
        int i = base + j;
        v[j] = (i < n) ? in[i] : 0;
        s += v[j];
    }
    lds[tid] = s; __syncthreads();
    for (int off = 1; off < 256; off <<= 1) {
        int t = (tid >= off) ? lds[tid - off] : 0;
        __syncthreads();
        lds[tid] += t;
        __syncthreads();
    }
    int ex = lds[tid] - s + bsum[blockIdx.x];
#pragma unroll
    for (int j = 0; j < 16; j++) {
        int i = base + j;
        if (i < n) { out[i] = ex; ex += v[j]; }
    }
}

// ===========================================================================
// Atomic-free bucket fill (4 edges/thread, same g mapping as hist_rank):
// pos = offs_gm[g][dst] + rank[e]; XCD-local write regions.
// ===========================================================================
__global__ __launch_bounds__(256)
void fill2_kernel(const int* __restrict__ src, const int* __restrict__ dst,
                  const int* __restrict__ offs_gm, const int* __restrict__ rank,
                  int* __restrict__ srcs_gm, int n_edges, int n_nodes, int G) {
    int base = blockIdx.x * 1024 + threadIdx.x;
    int g = blockIdx.x % G;
    const int* og = offs_gm + (size_t)g * n_nodes;
#pragma unroll
    for (int j = 0; j < 4; j++) {
        int t = base + j * 256;
        if (t < n_edges) {
            int d = dst[t];
            srcs_gm[og[d] + rank[t]] = src[t];
        }
    }
}

// ===========================================================================
// Reorder group-major srcs -> node-major srcs2 (one contiguous segment/node).
// ===========================================================================
__global__ __launch_bounds__(256)
void reorder_kernel(const int* __restrict__ offs_gm, const int* __restrict__ srcs_gm,
                    const int* __restrict__ node_offs, int* __restrict__ srcs2,
                    int n_nodes, int G) {
    int n = blockIdx.x * 256 + threadIdx.x;
    if (n >= n_nodes) return;
    int base = node_offs[n];
    for (int g = 0; g < G; g++) {
        int a = offs_gm[(size_t)g * n_nodes + n];
        int e = offs_gm[(size_t)g * n_nodes + n + 1];
        for (int i = a; i < e; i++) srcs2[base++] = srcs_gm[i];
    }
}

// ===========================================================================
// MFMA GEMM: H[n_rows x 64] = X[n_rows x K] @ W[K x 64], bf16 in, bf16 out.
// 64 rows/block, 256 threads = 4 waves; wave w owns rows [w*16, w*16+16).
// v_mfma_f32_16x16x32_bf16: A row=lane&15, k=(lane>>4)*8+j;
//                           D col=lane&15, row=(lane>>4)*4+reg.
// W staged TRANSPOSED in LDS so B fragments are contiguous 16B loads.
// IN = float (convert to bf16 during staging) or unsigned short (bf16 copy).
// ===========================================================================
template <int K, typename IN>
__global__ __launch_bounds__(256)
void gemm_mfma_kernel(const IN* __restrict__ X, const float* __restrict__ W,
                      unsigned short* __restrict__ H, int n_rows) {
    constexpr int KP = K + 8;   // ushort stride, multiple of 8 keeps 16B alignment
    __shared__ unsigned short As[64 * KP];
    __shared__ unsigned short Wt[64 * KP];

    const int tid  = threadIdx.x;
    const int row0 = blockIdx.x * 64;

    // stage W transposed: W[k][n] fp32 -> Wt[n*KP + k] bf16
    for (int i = tid; i < K * 64; i += 256) {
        int k = i >> 6;
        int n = i & 63;
        Wt[n * KP + k] = f2bf(W[i]);
    }
    // stage A tile (64 rows x K bf16)
    if constexpr (sizeof(IN) == 4) {
        constexpr int KQ = K / 4;
        for (int i = tid; i < 64 * KQ; i += 256) {
            int r = i / KQ, k4 = i % KQ;
            int row = row0 + r;
            float4 v = make_float4(0.f, 0.f, 0.f, 0.f);
            if (row < n_rows) v = ((const float4*)((const float*)X + (size_t)row * K))[k4];
            ushort4 o = make_ushort4(f2bf(v.x), f2bf(v.y), f2bf(v.z), f2bf(v.w));
            *(ushort4*)&As[r * KP + k4 * 4] = o;
        }
    } else {
        constexpr int KQ = K / 8;
        for (int i = tid; i < 64 * KQ; i += 256) {
            int r = i / KQ, k8 = i % KQ;
            int row = row0 + r;
            int4 v = make_int4(0, 0, 0, 0);
            if (row < n_rows) v = ((const int4*)((const unsigned short*)X + (size_t)row * K))[k8];
            *(int4*)&As[r * KP + k8 * 8] = v;
        }
    }
    __syncthreads();

    const int wave = tid >> 6;
    const int lane = tid & 63;
    const int lrow = lane & 15;
    const int quad = lane >> 4;
    const int m = wave * 16 + lrow;

    f32x4 acc0 = {0.f, 0.f, 0.f, 0.f};
    f32x4 acc1 = {0.f, 0.f, 0.f, 0.f};
    f32x4 acc2 = {0.f, 0.f, 0.f, 0.f};
    f32x4 acc3 = {0.f, 0.f, 0.f, 0.f};

#pragma unroll
    for (int kt = 0; kt < K / 32; kt++) {
        int k0 = kt * 32 + quad * 8;
        bf16x8 a = *(const bf16x8*)&As[m * KP + k0];
        bf16x8 b0 = *(const bf16x8*)&Wt[(0 * 16 + lrow) * KP + k0];
        bf16x8 b1 = *(const bf16x8*)&Wt[(1 * 16 + lrow) * KP + k0];
        bf16x8 b2 = *(const bf16x8*)&Wt[(2 * 16 + lrow) * KP + k0];
        bf16x8 b3 = *(const bf16x8*)&Wt[(3 * 16 + lrow) * KP + k0];
        acc0 = __builtin_amdgcn_mfma_f32_16x16x32_bf16(a, b0, acc0, 0, 0, 0);
        acc1 = __builtin_amdgcn_mfma_f32_16x16x32_bf16(a, b1, acc1, 0, 0, 0);
        acc2 = __builtin_amdgcn_mfma_f32_16x16x32_bf16(a, b2, acc2, 0, 0, 0);
        acc3 = __builtin_amdgcn_mfma_f32_16x16x32_bf16(a, b3, acc3, 0, 0, 0);
    }

    f32x4 accs[4] = {acc0, acc1, acc2, acc3};
#pragma unroll
    for (int c = 0; c < 4; c++) {
#pragma unroll
        for (int r = 0; r < 4; r++) {
            int row = row0 + wave * 16 + quad * 4 + r;
            if (row < n_rows) H[(size_t)row * 64 + c * 16 + lrow] = f2bf(accs[c][r]);
        }
    }
}

// ===========================================================================
// Flat CSR gather: 8 lanes/node, 8 channels/lane (int4 = 8 bf16 per load),
// x4 unrolled edge loop. Fused self-loop + bias + relu.
// OUT = float (layer 2, feeds pool) or unsigned short bf16 (layer 1, feeds GEMM2).
// ===========================================================================
__device__ inline void upk_fma(int4 u, float c, float* acc) {
    unsigned int a = (unsigned int)u.x, b = (unsigned int)u.y;
    unsigned int d = (unsigned int)u.z, e = (unsigned int)u.w;
    acc[0] += __uint_as_float(a << 16) * c;
    acc[1] += __uint_as_float(a & 0xFFFF0000u) * c;
    acc[2] += __uint_as_float(b << 16) * c;
    acc[3] += __uint_as_float(b & 0xFFFF0000u) * c;
    acc[4] += __uint_as_float(d << 16) * c;
    acc[5] += __uint_as_float(d & 0xFFFF0000u) * c;
    acc[6] += __uint_as_float(e << 16) * c;
    acc[7] += __uint_as_float(e & 0xFFFF0000u) * c;
}

template <typename OUT>
__global__ __launch_bounds__(256)
void gather_flat_kernel(const int* __restrict__ offs, const int* __restrict__ srcs,
                        const float* __restrict__ dinv, const unsigned short* __restrict__ h,
                        const float* __restrict__ b, OUT* __restrict__ out, int n_nodes) {
    int t = blockIdx.x * 256 + threadIdx.x;
    int node = t >> 3;
    if (node >= n_nodes) return;
    int cg = (t & 7) * 8;   // channel offset (ushorts)

    float dn = dinv[node];
    float acc[8];
    {
        int4 u = *(const int4*)(h + (size_t)node * 64 + cg);
        float c2 = dn * dn;
        for (int j = 0; j < 8; j++) acc[j] = 0.f;
        upk_fma(u, c2, acc);
    }

    int i  = offs[node];
    int i1 = offs[node + 1];
    for (; i + 4 <= i1; i += 4) {
        int s0 = srcs[i];
        int s1 = srcs[i + 1];
        int s2 = srcs[i + 2];
        int s3 = srcs[i + 3];
        float c0 = dinv[s0] * dn;
        float c1 = dinv[s1] * dn;
        float c2 = dinv[s2] * dn;
        float c3 = dinv[s3] * dn;
        int4 u0 = *(const int4*)(h + (size_t)s0 * 64 + cg);
        int4 u1 = *(const int4*)(h + (size_t)s1 * 64 + cg);
        int4 u2 = *(const int4*)(h + (size_t)s2 * 64 + cg);
        int4 u3 = *(const int4*)(h + (size_t)s3 * 64 + cg);
        upk_fma(u0, c0, acc);
        upk_fma(u1, c1, acc);
        upk_fma(u2, c2, acc);
        upk_fma(u3, c3, acc);
    }
    for (; i < i1; i++) {
        int s0 = srcs[i];
        float c0 = dinv[s0] * dn;
        int4 u0 = *(const int4*)(h + (size_t)s0 * 64 + cg);
        upk_fma(u0, c0, acc);
    }

    float4 b0 = *(const float4*)(b + cg);
    float4 b1 = *(const float4*)(b + cg + 4);
    float r[8];
    r[0] = fmaxf(acc[0] + b0.x, 0.f);
    r[1] = fmaxf(acc[1] + b0.y, 0.f);
    r[2] = fmaxf(acc[2] + b0.z, 0.f);
    r[3] = fmaxf(acc[3] + b0.w, 0.f);
    r[4] = fmaxf(acc[4] + b1.x, 0.f);
    r[5] = fmaxf(acc[5] + b1.y, 0.f);
    r[6] = fmaxf(acc[6] + b1.z, 0.f);
    r[7] = fmaxf(acc[7] + b1.w, 0.f);

    if constexpr (sizeof(OUT) == 4) {
        float* o = (float*)out + (size_t)node * 64 + cg;
        *(float4*)(o)     = make_float4(r[0], r[1], r[2], r[3]);
        *(float4*)(o + 4) = make_float4(r[4], r[5], r[6], r[7]);
    } else {
        unsigned short* o = (unsigned short*)out + (size_t)node * 64 + cg;
        ushort4 p0 = make_ushort4(f2bf(r[0]), f2bf(r[1]), f2bf(r[2]), f2bf(r[3]));
        ushort4 p1 = make_ushort4(f2bf(r[4]), f2bf(r[5]), f2bf(r[6]), f2bf(r[7]));
        *(ushort4*)(o)     = p0;
        *(ushort4*)(o + 4) = p1;
    }
}

// ===========================================================================
// Pooling (batch sorted): one wave per 32-node chunk; lane = channel.
// ===========================================================================
__global__ __launch_bounds__(256)
void pool_kernel(const float* __restrict__ h, const int* __restrict__ batch,
                 float* __restrict__ pooled, float* __restrict__ cnt,
                 int n_nodes, int chunk) {
    int wave = (blockIdx.x * blockDim.x + threadIdx.x) >> 6;
    int lane = threadIdx.x & 63;
    int start = wave * chunk;
    if (start >= n_nodes) return;
    int end = min(start + chunk, n_nodes);

    int cur = batch[start];
    float acc = 0.f;
    float c = 0.f;
    for (int i = start; i < end; i++) {
        int g = batch[i];
        if (g != cur) {
            unsafeAtomicAdd(&pooled[(size_t)cur * 64 + lane], acc);
            if (lane == 0) unsafeAtomicAdd(&cnt[cur], c);
            acc = 0.f; c = 0.f; cur = g;
        }
        acc += h[(size_t)i * 64 + lane];
        c += 1.f;
    }
    unsafeAtomicAdd(&pooled[(size_t)cur * 64 + lane], acc);
    if (lane == 0) unsafeAtomicAdd(&cnt[cur], c);
}

__global__ __launch_bounds__(256)
void head_kernel(const float* __restrict__ pooled, const float* __restrict__ cnt,
                 const float* __restrict__ Wfc, const float* __restrict__ bfc,
                 float* __restrict__ out) {
    __shared__ float Ws[HIDDEN * N_CLASSES];
    __shared__ float bs[N_CLASSES];
    int tid = threadIdx.x;
    for (int i = tid; i < HIDDEN * N_CLASSES; i += 256) Ws[i] = Wfc[i];
    if (tid < N_CLASSES) bs[tid] = bfc[tid];
    __syncthreads();

    int g = blockIdx.x * 256 + tid;
    if (g >= N_GRAPHS) return;

    float inv = 1.f / fmaxf(cnt[g], 1.f);
    float p[HIDDEN];
#pragma unroll
    for (int k = 0; k < HIDDEN; k++) p[k] = pooled[(size_t)g * 64 + k] * inv;

    float lg[N_CLASSES];
    float m = -1e30f;
#pragma unroll
    for (int j = 0; j < N_CLASSES; j++) {
        float a = bs[j];
#pragma unroll
        for (int k = 0; k < HIDDEN; k++) a += p[k] * Ws[k * N_CLASSES + j];
        lg[j] = a;
        m = fmaxf(m, a);
    }
    float s = 0.f;
#pragma unroll
    for (int j = 0; j < N_CLASSES; j++) s += __expf(lg[j] - m);
    float lse = m + __logf(s);
#pragma unroll
    for (int j = 0; j < N_CLASSES; j++) out[(size_t)g * N_CLASSES + j] = lg[j] - lse;
}

// ===========================================================================
// Launch
// ===========================================================================
extern "C" void kernel_launch(void* const* d_in, const int* in_sizes, int n_in,
                              void* d_out, int out_size, void* d_ws, size_t ws_size,
                              hipStream_t stream) {
    const float* x   = (const float*)d_in[0];
    const int*   ei  = (const int*)d_in[1];
    const int*   bat = (const int*)d_in[2];
    const float* W1  = (const float*)d_in[3];
    const float* b1  = (const float*)d_in[4];
    const float* W2  = (const float*)d_in[5];
    const float* b2  = (const float*)d_in[6];
    const float* Wfc = (const float*)d_in[7];
    const float* bfc = (const float*)d_in[8];
    float* out = (float*)d_out;

    const int* src = ei;
    const int* dst = ei + N_EDGES;

    char* ws = (char*)d_ws;

    // NEEDED(G) = 58,135,184 + 800,000*G   (unchanged; G=8 proven R3-R6)
    int G;
    if      (ws_size >= 58135184 + 800000 * (size_t)8) G = 8;
    else if (ws_size >= 58135184 + 800000 * (size_t)2) G = 2;
    else                                               G = 1;

    const size_t OFF_BUFA = 0;                                   // 25.6 MB region
    const size_t OFF_BUFB = 25600000;                            // 25.6 MB (rank during build; bf16 h1r; fp32 out2)
    const size_t OFF_DINV = 51200000;
    const size_t OFF_OFFS = 51600000;                            // G*400,000 + 16
    const size_t OFF_CURS = OFF_OFFS + (size_t)G * 400000 + 16;  // G*400,000 (degi)
    const size_t OFF_BSUM = OFF_CURS + (size_t)G * 400000;
    const size_t OFF_POOL = OFF_BSUM + 2048;
    const size_t OFF_CNT  = OFF_POOL + 131072;
    const size_t OFF_SRCS = OFF_CNT + 2048;                      // 6.4 MB group-major srcs

    // Sub-layout inside bufA region (h table uses only [0, 12.8 MB)):
    const size_t OFF_H     = OFF_BUFA;                // 12,800,000 bf16 h table
    const size_t OFF_SRCS2 = OFF_BUFA + 12800000;     //  6,400,000 node-major srcs
    const size_t OFF_NOFFS = OFF_BUFA + 19200000;     //    400,016 node offs (N+1)
    const size_t OFF_DEGS  = OFF_BUFA + 19600016;     //    400,000 degsum

    unsigned short* bufA = (unsigned short*)(ws + OFF_H);
    int*   srcs2  = (int*)  (ws + OFF_SRCS2);
    int*   noffs  = (int*)  (ws + OFF_NOFFS);
    int*   degsum = (int*)  (ws + OFF_DEGS);
    float* bufB   = (float*)(ws + OFF_BUFB);
    unsigned short* bufB16 = (unsigned short*)(ws + OFF_BUFB);
    int*   rank   = (int*)  (ws + OFF_BUFB);   // aliases bufB during CSR build only
    float* dinv   = (float*)(ws + OFF_DINV);
    int*   offs   = (int*)  (ws + OFF_OFFS);   // group-major offsets
    int*   degi   = (int*)  (ws + OFF_CURS);
    int*   bsum   = (int*)  (ws + OFF_BSUM);
    float* pooled = (float*)(ws + OFF_POOL);
    float* cnt    = (float*)(ws + OFF_CNT);
    int*   srcs   = (int*)  (ws + OFF_SRCS);   // group-major srcs

    const int GN = G * N_NODES;
    const int SCAN_BLOCKS_GN = (GN + 4095) / 4096;
    const int SCAN_BLOCKS_N  = (N_NODES + 4095) / 4096;
    const int EDGE_BLOCKS4 = (N_EDGES + 1023) / 1024;    // 1563 (4 edges/thread)
    const int NODE_BLOCKS = (N_NODES + 255) / 256;
    const int GATHER_BLOCKS = (N_NODES * 8 + 255) / 256;
    const int GEMM_BLOCKS = (N_NODES + 63) / 64;

    // --- build CSR ---
    hipMemsetAsync(degi, 0, (size_t)GN * sizeof(int), stream);
    hist_rank_kernel<<<EDGE_BLOCKS4, 256, 0, stream>>>(dst, degi, rank, N_EDGES, N_NODES, G);
    dinv_sum_kernel<<<NODE_BLOCKS, 256, 0, stream>>>(degi, dinv, degsum, N_NODES, G);
    scan1_kernel<<<SCAN_BLOCKS_GN, 256, 0, stream>>>(degi, bsum, GN);
    scan2_kernel<<<1, 256, 0, stream>>>(bsum, offs, SCAN_BLOCKS_GN, GN);
    scan3_kernel<<<SCAN_BLOCKS_GN, 256, 0, stream>>>(degi, bsum, offs, GN);
    scan1_kernel<<<SCAN_BLOCKS_N, 256, 0, stream>>>(degsum, bsum, N_NODES);
    scan2_kernel<<<1, 256, 0, stream>>>(bsum, noffs, SCAN_BLOCKS_N, N_NODES);
    scan3_kernel<<<SCAN_BLOCKS_N, 256, 0, stream>>>(degsum, bsum, noffs, N_NODES);
    fill2_kernel<<<EDGE_BLOCKS4, 256, 0, stream>>>(src, dst, offs, rank, srcs, N_EDGES, N_NODES, G);
    reorder_kernel<<<NODE_BLOCKS, 256, 0, stream>>>(offs, srcs, noffs, srcs2, N_NODES, G);

    // --- layer 1: h1 = x @ W1 (MFMA, bf16 out) ---
    gemm_mfma_kernel<D_IN, float><<<GEMM_BLOCKS, 256, 0, stream>>>(x, W1, bufA, N_NODES);
    gather_flat_kernel<unsigned short><<<GATHER_BLOCKS, 256, 0, stream>>>(
        noffs, srcs2, dinv, bufA, b1, bufB16, N_NODES);

    // --- layer 2: h2 = h1r @ W2 (MFMA, bf16 in/out) ---
    gemm_mfma_kernel<HIDDEN, unsigned short><<<GEMM_BLOCKS, 256, 0, stream>>>(bufB16, W2, bufA, N_NODES);
    gather_flat_kernel<float><<<GATHER_BLOCKS, 256, 0, stream>>>(
        noffs, srcs2, dinv, bufA, b2, bufB, N_NODES);

    // --- pooling + head ---
    hipMemsetAsync(pooled, 0, (size_t)N_GRAPHS * 64 * sizeof(float), stream);
    hipMemsetAsync(cnt, 0, (size_t)N_GRAPHS * sizeof(float), stream);
    {
        const int chunk = 32;
        int waves  = (N_NODES + chunk - 1) / chunk;
        int blocks = (waves + 3) / 4;
        pool_kernel<<<blocks, 256, 0, stream>>>(bufB, bat, pooled, cnt, N_NODES, chunk);
    }
    head_kernel<<<(N_GRAPHS + 255) / 256, 256, 0, stream>>>(pooled, cnt, Wfc, bfc, out);
}

// Round 8
// 308.554 us; speedup vs baseline: 1.9186x; 1.1227x over previous
//
#include <hip/hip_runtime.h>
#include <cstdint>
#include <cstddef>

#define N_NODES   100000
#define N_EDGES   1600000
#define D_IN      128
#define HIDDEN    64
#define N_GRAPHS  512
#define N_CLASSES 10
#define G         8

typedef __attribute__((ext_vector_type(8))) short bf16x8;
typedef __attribute__((ext_vector_type(4))) float f32x4;

// ---- bf16 helpers (RNE pack, bit-shift unpack) ----
__device__ inline float bf2f(unsigned short u) {
    return __uint_as_float(((unsigned int)u) << 16);
}
__device__ inline unsigned short f2bf(float f) {
    unsigned int x = __float_as_uint(f);
    return (unsigned short)((x + 0x7FFF + ((x >> 16) & 1)) >> 16);
}

// ===========================================================================
// Scan bodies (device functions, virtual block index). Branches on blockIdx
// are block-uniform, so __syncthreads inside is safe.
// ===========================================================================
__device__ __forceinline__
void scan1_body(int bid, int tid, const int* __restrict__ in, int* __restrict__ bsum, int n) {
    __shared__ int lds1[256];
    int base = bid * 4096 + tid * 16;
    int s = 0;
#pragma unroll
    for (int j = 0; j < 16; j++) { int i = base + j; if (i < n) s += in[i]; }
    lds1[tid] = s; __syncthreads();
    for (int off = 128; off > 0; off >>= 1) {
        if (tid < off) lds1[tid] += lds1[tid + off];
        __syncthreads();
    }
    if (tid == 0) bsum[bid] = lds1[0];
}

__device__ __forceinline__
void scan2_body(int tid, int* __restrict__ bsum, int* __restrict__ out, int nb, int n) {
    __shared__ int lds2[256];
    int v = (tid < nb) ? bsum[tid] : 0;
    lds2[tid] = v; __syncthreads();
    for (int off = 1; off < 256; off <<= 1) {
        int t = (tid >= off) ? lds2[tid - off] : 0;
        __syncthreads();
        lds2[tid] += t;
        __syncthreads();
    }
    if (tid < nb) bsum[tid] = lds2[tid] - v;   // exclusive block offsets
    if (tid == 255) out[n] = lds2[255];        // grand total
}

__device__ __forceinline__
void scan3_body(int bid, int tid, const int* __restrict__ in, const int* __restrict__ bsum,
                int* __restrict__ out, int n) {
    __shared__ int lds3[256];
    int base = bid * 4096 + tid * 16;
    int v[16]; int s = 0;
#pragma unroll
    for (int j = 0; j < 16; j++) {
        int i = base + j;
        v[j] = (i < n) ? in[i] : 0;
        s += v[j];
    }
    lds3[tid] = s; __syncthreads();
    for (int off = 1; off < 256; off <<= 1) {
        int t = (tid >= off) ? lds3[tid - off] : 0;
        __syncthreads();
        lds3[tid] += t;
        __syncthreads();
    }
    int ex = lds3[tid] - s + bsum[bid];
#pragma unroll
    for (int j = 0; j < 16; j++) {
        int i = base + j;
        if (i < n) { out[i] = ex; ex += v[j]; }
    }
}

// ===========================================================================
// Fused 1: even blocks = gemm1 tile (x fp32 @ W1 -> bf16 h), odd = hist+rank.
// hist is atomic-memory bound (VALU 0.5%) so gemm rides in its shadow.
// ===========================================================================
__global__ __launch_bounds__(256)
void fused1_kernel(const float* __restrict__ X, const float* __restrict__ W,
                   unsigned short* __restrict__ H,
                   const int* __restrict__ dst, int* __restrict__ degi,
                   int* __restrict__ rank) {
    const int tid = threadIdx.x;
    if ((blockIdx.x & 1) == 1) {
        // ---- hist + rank: 4 edges/thread; bucket g = hb % G (matches fill2) ----
        int hb = blockIdx.x >> 1;
        int base = hb * 1024 + tid;
        int g = hb % G;
        int* dg = degi + (size_t)g * N_NODES;
#pragma unroll
        for (int j = 0; j < 4; j++) {
            int t = base + j * 256;
            if (t < N_EDGES) rank[t] = atomicAdd(&dg[dst[t]], 1);
        }
        return;
    }

    // ---- gemm1: 64 rows x 64 cols, K=128, MFMA 16x16x32 bf16 ----
    constexpr int K  = D_IN;
    constexpr int KP = K + 8;
    __shared__ unsigned short As[64 * KP];
    __shared__ unsigned short Wt[64 * KP];

    const int row0 = (blockIdx.x >> 1) * 64;

    for (int i = tid; i < K * 64; i += 256) {
        int k = i >> 6;
        int n = i & 63;
        Wt[n * KP + k] = f2bf(W[i]);
    }
    constexpr int KQ = K / 4;
    for (int i = tid; i < 64 * KQ; i += 256) {
        int r = i / KQ, k4 = i % KQ;
        int row = row0 + r;
        float4 v = make_float4(0.f, 0.f, 0.f, 0.f);
        if (row < N_NODES) v = ((const float4*)(X + (size_t)row * K))[k4];
        ushort4 o = make_ushort4(f2bf(v.x), f2bf(v.y), f2bf(v.z), f2bf(v.w));
        *(ushort4*)&As[r * KP + k4 * 4] = o;
    }
    __syncthreads();

    const int wave = tid >> 6;
    const int lane = tid & 63;
    const int lrow = lane & 15;
    const int quad = lane >> 4;
    const int m = wave * 16 + lrow;

    f32x4 acc0 = {0.f, 0.f, 0.f, 0.f};
    f32x4 acc1 = {0.f, 0.f, 0.f, 0.f};
    f32x4 acc2 = {0.f, 0.f, 0.f, 0.f};
    f32x4 acc3 = {0.f, 0.f, 0.f, 0.f};

#pragma unroll
    for (int kt = 0; kt < K / 32; kt++) {
        int k0 = kt * 32 + quad * 8;
        bf16x8 a = *(const bf16x8*)&As[m * KP + k0];
        bf16x8 b0 = *(const bf16x8*)&Wt[(0 * 16 + lrow) * KP + k0];
        bf16x8 b1 = *(const bf16x8*)&Wt[(1 * 16 + lrow) * KP + k0];
        bf16x8 b2 = *(const bf16x8*)&Wt[(2 * 16 + lrow) * KP + k0];
        bf16x8 b3 = *(const bf16x8*)&Wt[(3 * 16 + lrow) * KP + k0];
        acc0 = __builtin_amdgcn_mfma_f32_16x16x32_bf16(a, b0, acc0, 0, 0, 0);
        acc1 = __builtin_amdgcn_mfma_f32_16x16x32_bf16(a, b1, acc1, 0, 0, 0);
        acc2 = __builtin_amdgcn_mfma_f32_16x16x32_bf16(a, b2, acc2, 0, 0, 0);
        acc3 = __builtin_amdgcn_mfma_f32_16x16x32_bf16(a, b3, acc3, 0, 0, 0);
    }

    f32x4 accs[4] = {acc0, acc1, acc2, acc3};
#pragma unroll
    for (int c = 0; c < 4; c++) {
#pragma unroll
        for (int r = 0; r < 4; r++) {
            int row = row0 + wave * 16 + quad * 4 + r;
            if (row < N_NODES) H[(size_t)row * 64 + c * 16 + lrow] = f2bf(accs[c][r]);
        }
    }
}

// ===========================================================================
// Fused 2: blocks [0,391) dinv+degsum; [391,587) scan1 over degi (GN)
// ===========================================================================
__global__ __launch_bounds__(256)
void fused2_kernel(const int* __restrict__ degi, float* __restrict__ dinv,
                   int* __restrict__ degsum, int* __restrict__ bsumGN) {
    int tid = threadIdx.x;
    if (blockIdx.x < 391) {
        int t = blockIdx.x * 256 + tid;
        if (t >= N_NODES) return;
        int s = 0;
        for (int g = 0; g < G; g++) s += degi[(size_t)g * N_NODES + t];
        dinv[t] = rsqrtf((float)s + 1.0f);
        degsum[t] = s;
    } else {
        scan1_body(blockIdx.x - 391, tid, degi, bsumGN, G * N_NODES);
    }
}

// Fused 3: block 0 = scan2(GN); blocks [1,26) = scan1 over degsum (N)
__global__ __launch_bounds__(256)
void fused3_kernel(int* __restrict__ bsumGN, int* __restrict__ offs,
                   const int* __restrict__ degsum, int* __restrict__ bsumN) {
    int tid = threadIdx.x;
    if (blockIdx.x == 0) scan2_body(tid, bsumGN, offs, 196, G * N_NODES);
    else                 scan1_body(blockIdx.x - 1, tid, degsum, bsumN, N_NODES);
}

// Fused 4: blocks [0,196) = scan3(GN)->offs; block 196 = scan2(N)
__global__ __launch_bounds__(256)
void fused4_kernel(const int* __restrict__ degi, const int* __restrict__ bsumGN,
                   int* __restrict__ offs, int* __restrict__ bsumN,
                   int* __restrict__ noffs) {
    int tid = threadIdx.x;
    if (blockIdx.x < 196) scan3_body(blockIdx.x, tid, degi, bsumGN, offs, G * N_NODES);
    else                  scan2_body(tid, bsumN, noffs, 25, N_NODES);
}

// Fused 5: blocks [0,1563) = fill2 (atomic-free scatter); [1563,1588) = scan3(N)
__global__ __launch_bounds__(256)
void fused5_kernel(const int* __restrict__ src, const int* __restrict__ dst,
                   const int* __restrict__ offs, const int* __restrict__ rank,
                   int* __restrict__ srcs_gm,
                   const int* __restrict__ degsum, const int* __restrict__ bsumN,
                   int* __restrict__ noffs) {
    int tid = threadIdx.x;
    if (blockIdx.x < 1563) {
        int fb = blockIdx.x;
        int base = fb * 1024 + tid;
        int g = fb % G;
        const int* og = offs + (size_t)g * N_NODES;
#pragma unroll
        for (int j = 0; j < 4; j++) {
            int t = base + j * 256;
            if (t < N_EDGES) {
                int d = dst[t];
                srcs_gm[og[d] + rank[t]] = src[t];
            }
        }
    } else {
        scan3_body(blockIdx.x - 1563, tid, degsum, bsumN, noffs, N_NODES);
    }
}

// ===========================================================================
// Reorder group-major srcs -> node-major srcs2 (one contiguous segment/node).
// ===========================================================================
__global__ __launch_bounds__(256)
void reorder_kernel(const int* __restrict__ offs_gm, const int* __restrict__ srcs_gm,
                    const int* __restrict__ node_offs, int* __restrict__ srcs2) {
    int n = blockIdx.x * 256 + threadIdx.x;
    if (n >= N_NODES) return;
    int base = node_offs[n];
    for (int g = 0; g < G; g++) {
        int a = offs_gm[(size_t)g * N_NODES + n];
        int e = offs_gm[(size_t)g * N_NODES + n + 1];
        for (int i = a; i < e; i++) srcs2[base++] = srcs_gm[i];
    }
}

// ===========================================================================
// MFMA GEMM (standalone, layer 2): bf16 in, bf16 out, K=64.
// ===========================================================================
template <int K>
__global__ __launch_bounds__(256)
void gemm_mfma_kernel(const unsigned short* __restrict__ X, const float* __restrict__ W,
                      unsigned short* __restrict__ H, int n_rows) {
    constexpr int KP = K + 8;
    __shared__ unsigned short As[64 * KP];
    __shared__ unsigned short Wt[64 * KP];

    const int tid  = threadIdx.x;
    const int row0 = blockIdx.x * 64;

    for (int i = tid; i < K * 64; i += 256) {
        int k = i >> 6;
        int n = i & 63;
        Wt[n * KP + k] = f2bf(W[i]);
    }
    constexpr int KQ = K / 8;
    for (int i = tid; i < 64 * KQ; i += 256) {
        int r = i / KQ, k8 = i % KQ;
        int row = row0 + r;
        int4 v = make_int4(0, 0, 0, 0);
        if (row < n_rows) v = ((const int4*)(X + (size_t)row * K))[k8];
        *(int4*)&As[r * KP + k8 * 8] = v;
    }
    __syncthreads();

    const int wave = tid >> 6;
    const int lane = tid & 63;
    const int lrow = lane & 15;
    const int quad = lane >> 4;
    const int m = wave * 16 + lrow;

    f32x4 acc0 = {0.f, 0.f, 0.f, 0.f};
    f32x4 acc1 = {0.f, 0.f, 0.f, 0.f};
    f32x4 acc2 = {0.f, 0.f, 0.f, 0.f};
    f32x4 acc3 = {0.f, 0.f, 0.f, 0.f};

#pragma unroll
    for (int kt = 0; kt < K / 32; kt++) {
        int k0 = kt * 32 + quad * 8;
        bf16x8 a = *(const bf16x8*)&As[m * KP + k0];
        bf16x8 b0 = *(const bf16x8*)&Wt[(0 * 16 + lrow) * KP + k0];
        bf16x8 b1 = *(const bf16x8*)&Wt[(1 * 16 + lrow) * KP + k0];
        bf16x8 b2 = *(const bf16x8*)&Wt[(2 * 16 + lrow) * KP + k0];
        bf16x8 b3 = *(const bf16x8*)&Wt[(3 * 16 + lrow) * KP + k0];
        acc0 = __builtin_amdgcn_mfma_f32_16x16x32_bf16(a, b0, acc0, 0, 0, 0);
        acc1 = __builtin_amdgcn_mfma_f32_16x16x32_bf16(a, b1, acc1, 0, 0, 0);
        acc2 = __builtin_amdgcn_mfma_f32_16x16x32_bf16(a, b2, acc2, 0, 0, 0);
        acc3 = __builtin_amdgcn_mfma_f32_16x16x32_bf16(a, b3, acc3, 0, 0, 0);
    }

    f32x4 accs[4] = {acc0, acc1, acc2, acc3};
#pragma unroll
    for (int c = 0; c < 4; c++) {
#pragma unroll
        for (int r = 0; r < 4; r++) {
            int row = row0 + wave * 16 + quad * 4 + r;
            if (row < n_rows) H[(size_t)row * 64 + c * 16 + lrow] = f2bf(accs[c][r]);
        }
    }
}

// ===========================================================================
// Flat CSR gather: 8 lanes/node, 8 channels/lane, x4 unrolled edge loop.
// Fused self-loop + bias + relu; bf16 output.
// ===========================================================================
__device__ inline void upk_fma(int4 u, float c, float* acc) {
    unsigned int a = (unsigned int)u.x, b = (unsigned int)u.y;
    unsigned int d = (unsigned int)u.z, e = (unsigned int)u.w;
    acc[0] += __uint_as_float(a << 16) * c;
    acc[1] += __uint_as_float(a & 0xFFFF0000u) * c;
    acc[2] += __uint_as_float(b << 16) * c;
    acc[3] += __uint_as_float(b & 0xFFFF0000u) * c;
    acc[4] += __uint_as_float(d << 16) * c;
    acc[5] += __uint_as_float(d & 0xFFFF0000u) * c;
    acc[6] += __uint_as_float(e << 16) * c;
    acc[7] += __uint_as_float(e & 0xFFFF0000u) * c;
}

__global__ __launch_bounds__(256)
void gather_flat_kernel(const int* __restrict__ offs, const int* __restrict__ srcs,
                        const float* __restrict__ dinv, const unsigned short* __restrict__ h,
                        const float* __restrict__ b, unsigned short* __restrict__ out,
                        int n_nodes) {
    int t = blockIdx.x * 256 + threadIdx.x;
    int node = t >> 3;
    if (node >= n_nodes) return;
    int cg = (t & 7) * 8;

    float dn = dinv[node];
    float acc[8];
    {
        int4 u = *(const int4*)(h + (size_t)node * 64 + cg);
        float c2 = dn * dn;
        for (int j = 0; j < 8; j++) acc[j] = 0.f;
        upk_fma(u, c2, acc);
    }

    int i  = offs[node];
    int i1 = offs[node + 1];
    for (; i + 4 <= i1; i += 4) {
        int s0 = srcs[i];
        int s1 = srcs[i + 1];
        int s2 = srcs[i + 2];
        int s3 = srcs[i + 3];
        float c0 = dinv[s0] * dn;
        float c1 = dinv[s1] * dn;
        float c2 = dinv[s2] * dn;
        float c3 = dinv[s3] * dn;
        int4 u0 = *(const int4*)(h + (size_t)s0 * 64 + cg);
        int4 u1 = *(const int4*)(h + (size_t)s1 * 64 + cg);
        int4 u2 = *(const int4*)(h + (size_t)s2 * 64 + cg);
        int4 u3 = *(const int4*)(h + (size_t)s3 * 64 + cg);
        upk_fma(u0, c0, acc);
        upk_fma(u1, c1, acc);
        upk_fma(u2, c2, acc);
        upk_fma(u3, c3, acc);
    }
    for (; i < i1; i++) {
        int s0 = srcs[i];
        float c0 = dinv[s0] * dn;
        int4 u0 = *(const int4*)(h + (size_t)s0 * 64 + cg);
        upk_fma(u0, c0, acc);
    }

    float4 b0 = *(const float4*)(b + cg);
    float4 b1 = *(const float4*)(b + cg + 4);
    unsigned short* o = out + (size_t)node * 64 + cg;
    ushort4 p0 = make_ushort4(f2bf(fmaxf(acc[0] + b0.x, 0.f)), f2bf(fmaxf(acc[1] + b0.y, 0.f)),
                              f2bf(fmaxf(acc[2] + b0.z, 0.f)), f2bf(fmaxf(acc[3] + b0.w, 0.f)));
    ushort4 p1 = make_ushort4(f2bf(fmaxf(acc[4] + b1.x, 0.f)), f2bf(fmaxf(acc[5] + b1.y, 0.f)),
                              f2bf(fmaxf(acc[6] + b1.z, 0.f)), f2bf(fmaxf(acc[7] + b1.w, 0.f)));
    *(ushort4*)(o)     = p0;
    *(ushort4*)(o + 4) = p1;
}

// ===========================================================================
// Pooling (batch sorted, bf16 input): one wave per 32-node chunk; lane=channel.
// ===========================================================================
__global__ __launch_bounds__(256)
void pool_kernel(const unsigned short* __restrict__ h, const int* __restrict__ batch,
                 float* __restrict__ pooled, float* __restrict__ cnt,
                 int n_nodes, int chunk) {
    int wave = (blockIdx.x * blockDim.x + threadIdx.x) >> 6;
    int lane = threadIdx.x & 63;
    int start = wave * chunk;
    if (start >= n_nodes) return;
    int end = min(start + chunk, n_nodes);

    int cur = batch[start];
    float acc = 0.f;
    float c = 0.f;
    for (int i = start; i < end; i++) {
        int g = batch[i];
        if (g != cur) {
            unsafeAtomicAdd(&pooled[(size_t)cur * 64 + lane], acc);
            if (lane == 0) unsafeAtomicAdd(&cnt[cur], c);
            acc = 0.f; c = 0.f; cur = g;
        }
        acc += bf2f(h[(size_t)i * 64 + lane]);
        c += 1.f;
    }
    unsafeAtomicAdd(&pooled[(size_t)cur * 64 + lane], acc);
    if (lane == 0) unsafeAtomicAdd(&cnt[cur], c);
}

__global__ __launch_bounds__(256)
void head_kernel(const float* __restrict__ pooled, const float* __restrict__ cnt,
                 const float* __restrict__ Wfc, const float* __restrict__ bfc,
                 float* __restrict__ out) {
    __shared__ float Ws[HIDDEN * N_CLASSES];
    __shared__ float bs[N_CLASSES];
    int tid = threadIdx.x;
    for (int i = tid; i < HIDDEN * N_CLASSES; i += 256) Ws[i] = Wfc[i];
    if (tid < N_CLASSES) bs[tid] = bfc[tid];
    __syncthreads();

    int g = blockIdx.x * 256 + tid;
    if (g >= N_GRAPHS) return;

    float inv = 1.f / fmaxf(cnt[g], 1.f);
    float p[HIDDEN];
#pragma unroll
    for (int k = 0; k < HIDDEN; k++) p[k] = pooled[(size_t)g * 64 + k] * inv;

    float lg[N_CLASSES];
    float m = -1e30f;
#pragma unroll
    for (int j = 0; j < N_CLASSES; j++) {
        float a = bs[j];
#pragma unroll
        for (int k = 0; k < HIDDEN; k++) a += p[k] * Ws[k * N_CLASSES + j];
        lg[j] = a;
        m = fmaxf(m, a);
    }
    float s = 0.f;
#pragma unroll
    for (int j = 0; j < N_CLASSES; j++) s += __expf(lg[j] - m);
    float lse = m + __logf(s);
#pragma unroll
    for (int j = 0; j < N_CLASSES; j++) out[(size_t)g * N_CLASSES + j] = lg[j] - lse;
}

// ===========================================================================
// Launch
// ===========================================================================
extern "C" void kernel_launch(void* const* d_in, const int* in_sizes, int n_in,
                              void* d_out, int out_size, void* d_ws, size_t ws_size,
                              hipStream_t stream) {
    const float* x   = (const float*)d_in[0];
    const int*   ei  = (const int*)d_in[1];
    const int*   bat = (const int*)d_in[2];
    const float* W1  = (const float*)d_in[3];
    const float* b1  = (const float*)d_in[4];
    const float* W2  = (const float*)d_in[5];
    const float* b2  = (const float*)d_in[6];
    const float* Wfc = (const float*)d_in[7];
    const float* bfc = (const float*)d_in[8];
    float* out = (float*)d_out;

    const int* src = ei;
    const int* dst = ei + N_EDGES;

    char* ws = (char*)d_ws;

    // Layout (total 64,535,184 B — identical footprint to R3-R7's G=8, proven):
    // bufA region [0, 25.6 MB): h table 12.8 MB | srcs2 6.4 MB | noffs | degsum
    const size_t OFF_H      = 0;
    const size_t OFF_SRCS2  = 12800000;
    const size_t OFF_NOFFS  = 19200000;   // 400,016
    const size_t OFF_DEGS   = 19600016;   // 400,000
    // bufB region [25.6, 51.2 MB): rank (build) -> h1r bf16 -> out2 bf16
    const size_t OFF_BUFB   = 25600000;
    const size_t OFF_DINV   = 51200000;   // 400,000
    const size_t OFF_OFFS   = 51600000;   // 8*400,000 + 16 = 3,200,016
    const size_t OFF_DEGI   = 54800016;   // 3,200,000
    const size_t OFF_BSUMGN = 58000016;   // 1,024
    const size_t OFF_BSUMN  = 58001040;   // 1,024
    const size_t OFF_POOL   = 58002064;   // 131,072
    const size_t OFF_CNT    = 58133136;   // 2,048
    const size_t OFF_SRCS   = 58135184;   // 6,400,000 (group-major srcs)

    unsigned short* hbuf   = (unsigned short*)(ws + OFF_H);
    int*   srcs2  = (int*)  (ws + OFF_SRCS2);
    int*   noffs  = (int*)  (ws + OFF_NOFFS);
    int*   degsum = (int*)  (ws + OFF_DEGS);
    unsigned short* bufB16 = (unsigned short*)(ws + OFF_BUFB);
    int*   rank   = (int*)  (ws + OFF_BUFB);   // aliases bufB during build only
    float* dinv   = (float*)(ws + OFF_DINV);
    int*   offs   = (int*)  (ws + OFF_OFFS);
    int*   degi   = (int*)  (ws + OFF_DEGI);
    int*   bsumGN = (int*)  (ws + OFF_BSUMGN);
    int*   bsumN  = (int*)  (ws + OFF_BSUMN);
    float* pooled = (float*)(ws + OFF_POOL);
    float* cnt    = (float*)(ws + OFF_CNT);
    int*   srcs   = (int*)  (ws + OFF_SRCS);

    const int GATHER_BLOCKS = (N_NODES * 8 + 255) / 256;  // 3125
    const int GEMM_BLOCKS = (N_NODES + 63) / 64;          // 1563

    hipMemsetAsync(degi, 0, (size_t)G * N_NODES * sizeof(int), stream);
    hipMemsetAsync(pooled, 0, (size_t)(N_GRAPHS * 64 + N_GRAPHS) * sizeof(float), stream);

    // 1. gemm1 (even blocks) + hist+rank (odd blocks); both sub-grids = 1563
    fused1_kernel<<<2 * GEMM_BLOCKS, 256, 0, stream>>>(x, W1, hbuf, dst, degi, rank);
    // 2. dinv+degsum (391) + scan1 GN (196)
    fused2_kernel<<<587, 256, 0, stream>>>(degi, dinv, degsum, bsumGN);
    // 3. scan2 GN (1) + scan1 N (25)
    fused3_kernel<<<26, 256, 0, stream>>>(bsumGN, offs, degsum, bsumN);
    // 4. scan3 GN (196) + scan2 N (1)
    fused4_kernel<<<197, 256, 0, stream>>>(degi, bsumGN, offs, bsumN, noffs);
    // 5. fill2 (1563) + scan3 N (25)
    fused5_kernel<<<1588, 256, 0, stream>>>(src, dst, offs, rank, srcs, degsum, bsumN, noffs);
    // 6. reorder -> node-major srcs2
    reorder_kernel<<<(N_NODES + 255) / 256, 256, 0, stream>>>(offs, srcs, noffs, srcs2);

    // 7. gather1: h(bufA) -> h1r bf16 (bufB; rank is dead)
    gather_flat_kernel<<<GATHER_BLOCKS, 256, 0, stream>>>(noffs, srcs2, dinv, hbuf, b1, bufB16, N_NODES);
    // 8. gemm2: h1r -> h2 bf16 (bufA h region)
    gemm_mfma_kernel<HIDDEN><<<GEMM_BLOCKS, 256, 0, stream>>>(bufB16, W2, hbuf, N_NODES);
    // 9. gather2: h2 -> out2 bf16 (bufB; h1r is dead)
    gather_flat_kernel<<<GATHER_BLOCKS, 256, 0, stream>>>(noffs, srcs2, dinv, hbuf, b2, bufB16, N_NODES);

    // 10. pool (bf16 in) + 11. head
    {
        const int chunk = 32;
        int waves  = (N_NODES + chunk - 1) / chunk;
        int blocks = (waves + 3) / 4;
        pool_kernel<<<blocks, 256, 0, stream>>>(bufB16, bat, pooled, cnt, N_NODES, chunk);
    }
    head_kernel<<<(N_GRAPHS + 255) / 256, 256, 0, stream>>>(pooled, cnt, Wfc, bfc, out);
}

// Round 9
// 303.106 us; speedup vs baseline: 1.9531x; 1.0180x over previous
//
#include <hip/hip_runtime.h>
#include <cstdint>
#include <cstddef>

#define N_NODES   100000
#define N_EDGES   1600000
#define D_IN      128
#define HIDDEN    64
#define N_GRAPHS  512
#define N_CLASSES 10
#define G         8

typedef __attribute__((ext_vector_type(8))) short bf16x8;
typedef __attribute__((ext_vector_type(4))) float f32x4;
typedef __attribute__((ext_vector_type(2))) float f32x2;

// ---- bf16 helpers (RNE pack, bit-shift unpack) ----
__device__ inline float bf2f(unsigned short u) {
    return __uint_as_float(((unsigned int)u) << 16);
}
__device__ inline unsigned short f2bf(float f) {
    unsigned int x = __float_as_uint(f);
    return (unsigned short)((x + 0x7FFF + ((x >> 16) & 1)) >> 16);
}

// ===========================================================================
// Scan bodies (device functions, virtual block index).
// ===========================================================================
__device__ __forceinline__
void scan1_body(int bid, int tid, const int* __restrict__ in, int* __restrict__ bsum, int n) {
    __shared__ int lds1[256];
    int base = bid * 4096 + tid * 16;
    int s = 0;
#pragma unroll
    for (int j = 0; j < 16; j++) { int i = base + j; if (i < n) s += in[i]; }
    lds1[tid] = s; __syncthreads();
    for (int off = 128; off > 0; off >>= 1) {
        if (tid < off) lds1[tid] += lds1[tid + off];
        __syncthreads();
    }
    if (tid == 0) bsum[bid] = lds1[0];
}

__device__ __forceinline__
void scan2_body(int tid, int* __restrict__ bsum, int* __restrict__ out, int nb, int n) {
    __shared__ int lds2[256];
    int v = (tid < nb) ? bsum[tid] : 0;
    lds2[tid] = v; __syncthreads();
    for (int off = 1; off < 256; off <<= 1) {
        int t = (tid >= off) ? lds2[tid - off] : 0;
        __syncthreads();
        lds2[tid] += t;
        __syncthreads();
    }
    if (tid < nb) bsum[tid] = lds2[tid] - v;
    if (tid == 255) out[n] = lds2[255];
}

__device__ __forceinline__
void scan3_body(int bid, int tid, const int* __restrict__ in, const int* __restrict__ bsum,
                int* __restrict__ out, int n) {
    __shared__ int lds3[256];
    int base = bid * 4096 + tid * 16;
    int v[16]; int s = 0;
#pragma unroll
    for (int j = 0; j < 16; j++) {
        int i = base + j;
        v[j] = (i < n) ? in[i] : 0;
        s += v[j];
    }
    lds3[tid] = s; __syncthreads();
    for (int off = 1; off < 256; off <<= 1) {
        int t = (tid >= off) ? lds3[tid - off] : 0;
        __syncthreads();
        lds3[tid] += t;
        __syncthreads();
    }
    int ex = lds3[tid] - s + bsum[bid];
#pragma unroll
    for (int j = 0; j < 16; j++) {
        int i = base + j;
        if (i < n) { out[i] = ex; ex += v[j]; }
    }
}

// ===========================================================================
// Fused 1: even blocks = gemm1 tile (x fp32 @ W1 -> bf16 h), odd = hist+rank.
// ===========================================================================
__global__ __launch_bounds__(256)
void fused1_kernel(const float* __restrict__ X, const float* __restrict__ W,
                   unsigned short* __restrict__ H,
                   const int* __restrict__ dst, int* __restrict__ degi,
                   int* __restrict__ rank) {
    const int tid = threadIdx.x;
    if ((blockIdx.x & 1) == 1) {
        int hb = blockIdx.x >> 1;
        int base = hb * 1024 + tid;
        int g = hb % G;
        int* dg = degi + (size_t)g * N_NODES;
#pragma unroll
        for (int j = 0; j < 4; j++) {
            int t = base + j * 256;
            if (t < N_EDGES) rank[t] = atomicAdd(&dg[dst[t]], 1);
        }
        return;
    }

    constexpr int K  = D_IN;
    constexpr int KP = K + 8;
    __shared__ unsigned short As[64 * KP];
    __shared__ unsigned short Wt[64 * KP];

    const int row0 = (blockIdx.x >> 1) * 64;

    for (int i = tid; i < K * 64; i += 256) {
        int k = i >> 6;
        int n = i & 63;
        Wt[n * KP + k] = f2bf(W[i]);
    }
    constexpr int KQ = K / 4;
    for (int i = tid; i < 64 * KQ; i += 256) {
        int r = i / KQ, k4 = i % KQ;
        int row = row0 + r;
        float4 v = make_float4(0.f, 0.f, 0.f, 0.f);
        if (row < N_NODES) v = ((const float4*)(X + (size_t)row * K))[k4];
        ushort4 o = make_ushort4(f2bf(v.x), f2bf(v.y), f2bf(v.z), f2bf(v.w));
        *(ushort4*)&As[r * KP + k4 * 4] = o;
    }
    __syncthreads();

    const int wave = tid >> 6;
    const int lane = tid & 63;
    const int lrow = lane & 15;
    const int quad = lane >> 4;
    const int m = wave * 16 + lrow;

    f32x4 acc0 = {0.f, 0.f, 0.f, 0.f};
    f32x4 acc1 = {0.f, 0.f, 0.f, 0.f};
    f32x4 acc2 = {0.f, 0.f, 0.f, 0.f};
    f32x4 acc3 = {0.f, 0.f, 0.f, 0.f};

#pragma unroll
    for (int kt = 0; kt < K / 32; kt++) {
        int k0 = kt * 32 + quad * 8;
        bf16x8 a = *(const bf16x8*)&As[m * KP + k0];
        bf16x8 b0 = *(const bf16x8*)&Wt[(0 * 16 + lrow) * KP + k0];
        bf16x8 b1 = *(const bf16x8*)&Wt[(1 * 16 + lrow) * KP + k0];
        bf16x8 b2 = *(const bf16x8*)&Wt[(2 * 16 + lrow) * KP + k0];
        bf16x8 b3 = *(const bf16x8*)&Wt[(3 * 16 + lrow) * KP + k0];
        acc0 = __builtin_amdgcn_mfma_f32_16x16x32_bf16(a, b0, acc0, 0, 0, 0);
        acc1 = __builtin_amdgcn_mfma_f32_16x16x32_bf16(a, b1, acc1, 0, 0, 0);
        acc2 = __builtin_amdgcn_mfma_f32_16x16x32_bf16(a, b2, acc2, 0, 0, 0);
        acc3 = __builtin_amdgcn_mfma_f32_16x16x32_bf16(a, b3, acc3, 0, 0, 0);
    }

    f32x4 accs[4] = {acc0, acc1, acc2, acc3};
#pragma unroll
    for (int c = 0; c < 4; c++) {
#pragma unroll
        for (int r = 0; r < 4; r++) {
            int row = row0 + wave * 16 + quad * 4 + r;
            if (row < N_NODES) H[(size_t)row * 64 + c * 16 + lrow] = f2bf(accs[c][r]);
        }
    }
}

// Fused 2: blocks [0,391) dinv+degsum; [391,587) scan1 over degi (GN)
__global__ __launch_bounds__(256)
void fused2_kernel(const int* __restrict__ degi, float* __restrict__ dinv,
                   int* __restrict__ degsum, int* __restrict__ bsumGN) {
    int tid = threadIdx.x;
    if (blockIdx.x < 391) {
        int t = blockIdx.x * 256 + tid;
        if (t >= N_NODES) return;
        int s = 0;
        for (int g = 0; g < G; g++) s += degi[(size_t)g * N_NODES + t];
        dinv[t] = rsqrtf((float)s + 1.0f);
        degsum[t] = s;
    } else {
        scan1_body(blockIdx.x - 391, tid, degi, bsumGN, G * N_NODES);
    }
}

// Fused 3: block 0 = scan2(GN); blocks [1,26) = scan1 over degsum (N)
__global__ __launch_bounds__(256)
void fused3_kernel(int* __restrict__ bsumGN, int* __restrict__ offs,
                   const int* __restrict__ degsum, int* __restrict__ bsumN) {
    int tid = threadIdx.x;
    if (blockIdx.x == 0) scan2_body(tid, bsumGN, offs, 196, G * N_NODES);
    else                 scan1_body(blockIdx.x - 1, tid, degsum, bsumN, N_NODES);
}

// Fused 4: blocks [0,196) = scan3(GN)->offs; block 196 = scan2(N)
__global__ __launch_bounds__(256)
void fused4_kernel(const int* __restrict__ degi, const int* __restrict__ bsumGN,
                   int* __restrict__ offs, int* __restrict__ bsumN,
                   int* __restrict__ noffs) {
    int tid = threadIdx.x;
    if (blockIdx.x < 196) scan3_body(blockIdx.x, tid, degi, bsumGN, offs, G * N_NODES);
    else                  scan2_body(tid, bsumN, noffs, 25, N_NODES);
}

// Fused 5: blocks [0,1563) = fill2 (atomic-free scatter); [1563,1588) = scan3(N)
__global__ __launch_bounds__(256)
void fused5_kernel(const int* __restrict__ src, const int* __restrict__ dst,
                   const int* __restrict__ offs, const int* __restrict__ rank,
                   int* __restrict__ srcs_gm,
                   const int* __restrict__ degsum, const int* __restrict__ bsumN,
                   int* __restrict__ noffs) {
    int tid = threadIdx.x;
    if (blockIdx.x < 1563) {
        int fb = blockIdx.x;
        int base = fb * 1024 + tid;
        int g = fb % G;
        const int* og = offs + (size_t)g * N_NODES;
#pragma unroll
        for (int j = 0; j < 4; j++) {
            int t = base + j * 256;
            if (t < N_EDGES) {
                int d = dst[t];
                srcs_gm[og[d] + rank[t]] = src[t];
            }
        }
    } else {
        scan3_body(blockIdx.x - 1563, tid, degsum, bsumN, noffs, N_NODES);
    }
}

// ===========================================================================
// LDS-staged reorder: block handles 256 nodes. Its 8 group-segments are
// contiguous runs in srcs_gm -> cooperative coalesced copy into LDS, then
// per-node assembly into node-major srcs2. Capacity-guarded w/ fallback.
// ===========================================================================
#define RCAP 10240   // 40 KB of LDS; expected run total ~4096 ints
__global__ __launch_bounds__(256)
void reorder2_kernel(const int* __restrict__ offs_gm, const int* __restrict__ srcs_gm,
                     const int* __restrict__ noffs, int* __restrict__ srcs2) {
    __shared__ int seg[RCAP];
    int tid = threadIdx.x;
    int n0 = blockIdx.x * 256;
    int n0e = min(n0 + 256, N_NODES);

    int total = noffs[n0e] - noffs[n0];

    int s_g[G], base_g[G];
    int acc = 0;
#pragma unroll
    for (int g = 0; g < G; g++) {
        s_g[g] = offs_gm[(size_t)g * N_NODES + n0];
        int e = offs_gm[(size_t)g * N_NODES + n0e];
        base_g[g] = acc;
        acc += e - s_g[g];
    }

    if (total <= RCAP) {
#pragma unroll
        for (int g = 0; g < G; g++) {
            int len = (g + 1 < G ? base_g[g + 1] : total) - base_g[g];
            for (int i = tid; i < len; i += 256) seg[base_g[g] + i] = srcs_gm[s_g[g] + i];
        }
        __syncthreads();
        int n = n0 + tid;
        if (n < N_NODES) {
            int w = noffs[n];
#pragma unroll
            for (int g = 0; g < G; g++) {
                int a = offs_gm[(size_t)g * N_NODES + n];
                int e = offs_gm[(size_t)g * N_NODES + n + 1];
                int l = a - s_g[g] + base_g[g];
                for (int i = a; i < e; i++) srcs2[w++] = seg[l++];
            }
        }
    } else {
        // fallback: per-thread direct (never expected at this degree distribution)
        int n = n0 + tid;
        if (n < N_NODES) {
            int w = noffs[n];
#pragma unroll
            for (int g = 0; g < G; g++) {
                int a = offs_gm[(size_t)g * N_NODES + n];
                int e = offs_gm[(size_t)g * N_NODES + n + 1];
                for (int i = a; i < e; i++) srcs2[w++] = srcs_gm[i];
            }
        }
    }
}

// ===========================================================================
// MFMA GEMM (layer 2): bf16 in, fp8-e4m3 out (HW cvt), K=64.
// ===========================================================================
template <int K>
__global__ __launch_bounds__(256)
void gemm_mfma_fp8out_kernel(const unsigned short* __restrict__ X, const float* __restrict__ W,
                             unsigned char* __restrict__ H8, int n_rows) {
    constexpr int KP = K + 8;
    __shared__ unsigned short As[64 * KP];
    __shared__ unsigned short Wt[64 * KP];

    const int tid  = threadIdx.x;
    const int row0 = blockIdx.x * 64;

    for (int i = tid; i < K * 64; i += 256) {
        int k = i >> 6;
        int n = i & 63;
        Wt[n * KP + k] = f2bf(W[i]);
    }
    constexpr int KQ = K / 8;
    for (int i = tid; i < 64 * KQ; i += 256) {
        int r = i / KQ, k8 = i % KQ;
        int row = row0 + r;
        int4 v = make_int4(0, 0, 0, 0);
        if (row < n_rows) v = ((const int4*)(X + (size_t)row * K))[k8];
        *(int4*)&As[r * KP + k8 * 8] = v;
    }
    __syncthreads();

    const int wave = tid >> 6;
    const int lane = tid & 63;
    const int lrow = lane & 15;
    const int quad = lane >> 4;
    const int m = wave * 16 + lrow;

    f32x4 acc0 = {0.f, 0.f, 0.f, 0.f};
    f32x4 acc1 = {0.f, 0.f, 0.f, 0.f};
    f32x4 acc2 = {0.f, 0.f, 0.f, 0.f};
    f32x4 acc3 = {0.f, 0.f, 0.f, 0.f};

#pragma unroll
    for (int kt = 0; kt < K / 32; kt++) {
        int k0 = kt * 32 + quad * 8;
        bf16x8 a = *(const bf16x8*)&As[m * KP + k0];
        bf16x8 b0 = *(const bf16x8*)&Wt[(0 * 16 + lrow) * KP + k0];
        bf16x8 b1 = *(const bf16x8*)&Wt[(1 * 16 + lrow) * KP + k0];
        bf16x8 b2 = *(const bf16x8*)&Wt[(2 * 16 + lrow) * KP + k0];
        bf16x8 b3 = *(const bf16x8*)&Wt[(3 * 16 + lrow) * KP + k0];
        acc0 = __builtin_amdgcn_mfma_f32_16x16x32_bf16(a, b0, acc0, 0, 0, 0);
        acc1 = __builtin_amdgcn_mfma_f32_16x16x32_bf16(a, b1, acc1, 0, 0, 0);
        acc2 = __builtin_amdgcn_mfma_f32_16x16x32_bf16(a, b2, acc2, 0, 0, 0);
        acc3 = __builtin_amdgcn_mfma_f32_16x16x32_bf16(a, b3, acc3, 0, 0, 0);
    }

    f32x4 accs[4] = {acc0, acc1, acc2, acc3};
#pragma unroll
    for (int c = 0; c < 4; c++) {
#pragma unroll
        for (int r = 0; r < 4; r++) {
            int row = row0 + wave * 16 + quad * 4 + r;
            if (row < n_rows) {
                int p = __builtin_amdgcn_cvt_pk_fp8_f32(accs[c][r], accs[c][r], 0, false);
                H8[(size_t)row * 64 + c * 16 + lrow] = (unsigned char)(p & 0xFF);
            }
        }
    }
}

// ===========================================================================
// Gather variant A (layer 1): bf16 h table, bf16 out. 8 lanes/node.
// ===========================================================================
__device__ inline void upk_fma(int4 u, float c, float* acc) {
    unsigned int a = (unsigned int)u.x, b = (unsigned int)u.y;
    unsigned int d = (unsigned int)u.z, e = (unsigned int)u.w;
    acc[0] += __uint_as_float(a << 16) * c;
    acc[1] += __uint_as_float(a & 0xFFFF0000u) * c;
    acc[2] += __uint_as_float(b << 16) * c;
    acc[3] += __uint_as_float(b & 0xFFFF0000u) * c;
    acc[4] += __uint_as_float(d << 16) * c;
    acc[5] += __uint_as_float(d & 0xFFFF0000u) * c;
    acc[6] += __uint_as_float(e << 16) * c;
    acc[7] += __uint_as_float(e & 0xFFFF0000u) * c;
}

__global__ __launch_bounds__(256)
void gather_flat_kernel(const int* __restrict__ offs, const int* __restrict__ srcs,
                        const float* __restrict__ dinv, const unsigned short* __restrict__ h,
                        const float* __restrict__ b, unsigned short* __restrict__ out,
                        int n_nodes) {
    int t = blockIdx.x * 256 + threadIdx.x;
    int node = t >> 3;
    if (node >= n_nodes) return;
    int cg = (t & 7) * 8;

    float dn = dinv[node];
    float acc[8];
    {
        int4 u = *(const int4*)(h + (size_t)node * 64 + cg);
        float c2 = dn * dn;
        for (int j = 0; j < 8; j++) acc[j] = 0.f;
        upk_fma(u, c2, acc);
    }

    int i  = offs[node];
    int i1 = offs[node + 1];
    for (; i + 4 <= i1; i += 4) {
        int s0 = srcs[i];
        int s1 = srcs[i + 1];
        int s2 = srcs[i + 2];
        int s3 = srcs[i + 3];
        float c0 = dinv[s0] * dn;
        float c1 = dinv[s1] * dn;
        float c2 = dinv[s2] * dn;
        float c3 = dinv[s3] * dn;
        int4 u0 = *(const int4*)(h + (size_t)s0 * 64 + cg);
        int4 u1 = *(const int4*)(h + (size_t)s1 * 64 + cg);
        int4 u2 = *(const int4*)(h + (size_t)s2 * 64 + cg);
        int4 u3 = *(const int4*)(h + (size_t)s3 * 64 + cg);
        upk_fma(u0, c0, acc);
        upk_fma(u1, c1, acc);
        upk_fma(u2, c2, acc);
        upk_fma(u3, c3, acc);
    }
    for (; i < i1; i++) {
        int s0 = srcs[i];
        float c0 = dinv[s0] * dn;
        int4 u0 = *(const int4*)(h + (size_t)s0 * 64 + cg);
        upk_fma(u0, c0, acc);
    }

    float4 b0 = *(const float4*)(b + cg);
    float4 b1 = *(const float4*)(b + cg + 4);
    unsigned short* o = out + (size_t)node * 64 + cg;
    ushort4 p0 = make_ushort4(f2bf(fmaxf(acc[0] + b0.x, 0.f)), f2bf(fmaxf(acc[1] + b0.y, 0.f)),
                              f2bf(fmaxf(acc[2] + b0.z, 0.f)), f2bf(fmaxf(acc[3] + b0.w, 0.f)));
    ushort4 p1 = make_ushort4(f2bf(fmaxf(acc[4] + b1.x, 0.f)), f2bf(fmaxf(acc[5] + b1.y, 0.f)),
                              f2bf(fmaxf(acc[6] + b1.z, 0.f)), f2bf(fmaxf(acc[7] + b1.w, 0.f)));
    *(ushort4*)(o)     = p0;
    *(ushort4*)(o + 4) = p1;
}

// ===========================================================================
// Gather variant B (layer 2): fp8-e4m3 h table (8 B/lane rows, HW cvt),
// bf16 out for pool.
// ===========================================================================
__device__ inline void upk8_fma(int2 u, float c, float* acc) {
    f32x2 p0 = __builtin_amdgcn_cvt_pk_f32_fp8(u.x, false);
    f32x2 p1 = __builtin_amdgcn_cvt_pk_f32_fp8(u.x, true);
    f32x2 p2 = __builtin_amdgcn_cvt_pk_f32_fp8(u.y, false);
    f32x2 p3 = __builtin_amdgcn_cvt_pk_f32_fp8(u.y, true);
    acc[0] += p0.x * c; acc[1] += p0.y * c;
    acc[2] += p1.x * c; acc[3] += p1.y * c;
    acc[4] += p2.x * c; acc[5] += p2.y * c;
    acc[6] += p3.x * c; acc[7] += p3.y * c;
}

__global__ __launch_bounds__(256)
void gather_fp8_kernel(const int* __restrict__ offs, const int* __restrict__ srcs,
                       const float* __restrict__ dinv, const unsigned char* __restrict__ h8,
                       const float* __restrict__ b, unsigned short* __restrict__ out,
                       int n_nodes) {
    int t = blockIdx.x * 256 + threadIdx.x;
    int node = t >> 3;
    if (node >= n_nodes) return;
    int cg = (t & 7) * 8;   // channel offset (bytes)

    float dn = dinv[node];
    float acc[8];
    {
        int2 u = *(const int2*)(h8 + (size_t)node * 64 + cg);
        float c2 = dn * dn;
        for (int j = 0; j < 8; j++) acc[j] = 0.f;
        upk8_fma(u, c2, acc);
    }

    int i  = offs[node];
    int i1 = offs[node + 1];
    for (; i + 4 <= i1; i += 4) {
        int s0 = srcs[i];
        int s1 = srcs[i + 1];
        int s2 = srcs[i + 2];
        int s3 = srcs[i + 3];
        float c0 = dinv[s0] * dn;
        float c1 = dinv[s1] * dn;
        float c2 = dinv[s2] * dn;
        float c3 = dinv[s3] * dn;
        int2 u0 = *(const int2*)(h8 + (size_t)s0 * 64 + cg);
        int2 u1 = *(const int2*)(h8 + (size_t)s1 * 64 + cg);
        int2 u2 = *(const int2*)(h8 + (size_t)s2 * 64 + cg);
        int2 u3 = *(const int2*)(h8 + (size_t)s3 * 64 + cg);
        upk8_fma(u0, c0, acc);
        upk8_fma(u1, c1, acc);
        upk8_fma(u2, c2, acc);
        upk8_fma(u3, c3, acc);
    }
    for (; i < i1; i++) {
        int s0 = srcs[i];
        float c0 = dinv[s0] * dn;
        int2 u0 = *(const int2*)(h8 + (size_t)s0 * 64 + cg);
        upk8_fma(u0, c0, acc);
    }

    float4 b0 = *(const float4*)(b + cg);
    float4 b1 = *(const float4*)(b + cg + 4);
    unsigned short* o = out + (size_t)node * 64 + cg;
    ushort4 p0 = make_ushort4(f2bf(fmaxf(acc[0] + b0.x, 0.f)), f2bf(fmaxf(acc[1] + b0.y, 0.f)),
                              f2bf(fmaxf(acc[2] + b0.z, 0.f)), f2bf(fmaxf(acc[3] + b0.w, 0.f)));
    ushort4 p1 = make_ushort4(f2bf(fmaxf(acc[4] + b1.x, 0.f)), f2bf(fmaxf(acc[5] + b1.y, 0.f)),
                              f2bf(fmaxf(acc[6] + b1.z, 0.f)), f2bf(fmaxf(acc[7] + b1.w, 0.f)));
    *(ushort4*)(o)     = p0;
    *(ushort4*)(o + 4) = p1;
}

// ===========================================================================
// Pooling (batch sorted, bf16 input) + head
// ===========================================================================
__global__ __launch_bounds__(256)
void pool_kernel(const unsigned short* __restrict__ h, const int* __restrict__ batch,
                 float* __restrict__ pooled, float* __restrict__ cnt,
                 int n_nodes, int chunk) {
    int wave = (blockIdx.x * blockDim.x + threadIdx.x) >> 6;
    int lane = threadIdx.x & 63;
    int start = wave * chunk;
    if (start >= n_nodes) return;
    int end = min(start + chunk, n_nodes);

    int cur = batch[start];
    float acc = 0.f;
    float c = 0.f;
    for (int i = start; i < end; i++) {
        int g = batch[i];
        if (g != cur) {
            unsafeAtomicAdd(&pooled[(size_t)cur * 64 + lane], acc);
            if (lane == 0) unsafeAtomicAdd(&cnt[cur], c);
            acc = 0.f; c = 0.f; cur = g;
        }
        acc += bf2f(h[(size_t)i * 64 + lane]);
        c += 1.f;
    }
    unsafeAtomicAdd(&pooled[(size_t)cur * 64 + lane], acc);
    if (lane == 0) unsafeAtomicAdd(&cnt[cur], c);
}

__global__ __launch_bounds__(256)
void head_kernel(const float* __restrict__ pooled, const float* __restrict__ cnt,
                 const float* __restrict__ Wfc, const float* __restrict__ bfc,
                 float* __restrict__ out) {
    __shared__ float Ws[HIDDEN * N_CLASSES];
    __shared__ float bs[N_CLASSES];
    int tid = threadIdx.x;
    for (int i = tid; i < HIDDEN * N_CLASSES; i += 256) Ws[i] = Wfc[i];
    if (tid < N_CLASSES) bs[tid] = bfc[tid];
    __syncthreads();

    int g = blockIdx.x * 256 + tid;
    if (g >= N_GRAPHS) return;

    float inv = 1.f / fmaxf(cnt[g], 1.f);
    float p[HIDDEN];
#pragma unroll
    for (int k = 0; k < HIDDEN; k++) p[k] = pooled[(size_t)g * 64 + k] * inv;

    float lg[N_CLASSES];
    float m = -1e30f;
#pragma unroll
    for (int j = 0; j < N_CLASSES; j++) {
        float a = bs[j];
#pragma unroll
        for (int k = 0; k < HIDDEN; k++) a += p[k] * Ws[k * N_CLASSES + j];
        lg[j] = a;
        m = fmaxf(m, a);
    }
    float s = 0.f;
#pragma unroll
    for (int j = 0; j < N_CLASSES; j++) s += __expf(lg[j] - m);
    float lse = m + __logf(s);
#pragma unroll
    for (int j = 0; j < N_CLASSES; j++) out[(size_t)g * N_CLASSES + j] = lg[j] - lse;
}

// ===========================================================================
// Launch
// ===========================================================================
extern "C" void kernel_launch(void* const* d_in, const int* in_sizes, int n_in,
                              void* d_out, int out_size, void* d_ws, size_t ws_size,
                              hipStream_t stream) {
    const float* x   = (const float*)d_in[0];
    const int*   ei  = (const int*)d_in[1];
    const int*   bat = (const int*)d_in[2];
    const float* W1  = (const float*)d_in[3];
    const float* b1  = (const float*)d_in[4];
    const float* W2  = (const float*)d_in[5];
    const float* b2  = (const float*)d_in[6];
    const float* Wfc = (const float*)d_in[7];
    const float* bfc = (const float*)d_in[8];
    float* out = (float*)d_out;

    const int* src = ei;
    const int* dst = ei + N_EDGES;

    char* ws = (char*)d_ws;

    // Layout (identical footprint to R8, proven):
    const size_t OFF_H      = 0;          // h1 bf16 12.8 MB; later h2 fp8 6.4 MB
    const size_t OFF_SRCS2  = 12800000;   // node-major srcs 6.4 MB
    const size_t OFF_NOFFS  = 19200000;   // 400,016
    const size_t OFF_DEGS   = 19600016;   // 400,000
    const size_t OFF_BUFB   = 25600000;   // rank (build) -> h1r bf16 -> out2 bf16
    const size_t OFF_DINV   = 51200000;   // 400,000
    const size_t OFF_OFFS   = 51600000;   // 3,200,016
    const size_t OFF_DEGI   = 54800016;   // 3,200,000
    const size_t OFF_BSUMGN = 58000016;   // 1,024
    const size_t OFF_BSUMN  = 58001040;   // 1,024
    const size_t OFF_POOL   = 58002064;   // 131,072
    const size_t OFF_CNT    = 58133136;   // 2,048
    const size_t OFF_SRCS   = 58135184;   // 6,400,000 (group-major srcs)

    unsigned short* hbuf   = (unsigned short*)(ws + OFF_H);
    unsigned char*  hbuf8  = (unsigned char*) (ws + OFF_H);
    int*   srcs2  = (int*)  (ws + OFF_SRCS2);
    int*   noffs  = (int*)  (ws + OFF_NOFFS);
    int*   degsum = (int*)  (ws + OFF_DEGS);
    unsigned short* bufB16 = (unsigned short*)(ws + OFF_BUFB);
    int*   rank   = (int*)  (ws + OFF_BUFB);
    float* dinv   = (float*)(ws + OFF_DINV);
    int*   offs   = (int*)  (ws + OFF_OFFS);
    int*   degi   = (int*)  (ws + OFF_DEGI);
    int*   bsumGN = (int*)  (ws + OFF_BSUMGN);
    int*   bsumN  = (int*)  (ws + OFF_BSUMN);
    float* pooled = (float*)(ws + OFF_POOL);
    float* cnt    = (float*)(ws + OFF_CNT);
    int*   srcs   = (int*)  (ws + OFF_SRCS);

    const int GATHER_BLOCKS = (N_NODES * 8 + 255) / 256;  // 3125
    const int GEMM_BLOCKS = (N_NODES + 63) / 64;          // 1563

    hipMemsetAsync(degi, 0, (size_t)G * N_NODES * sizeof(int), stream);
    hipMemsetAsync(pooled, 0, (size_t)(N_GRAPHS * 64 + N_GRAPHS) * sizeof(float), stream);

    // 1. gemm1 (even blocks) + hist+rank (odd blocks)
    fused1_kernel<<<2 * GEMM_BLOCKS, 256, 0, stream>>>(x, W1, hbuf, dst, degi, rank);
    // 2-5. scan chain + fill (unchanged from R8)
    fused2_kernel<<<587, 256, 0, stream>>>(degi, dinv, degsum, bsumGN);
    fused3_kernel<<<26, 256, 0, stream>>>(bsumGN, offs, degsum, bsumN);
    fused4_kernel<<<197, 256, 0, stream>>>(degi, bsumGN, offs, bsumN, noffs);
    fused5_kernel<<<1588, 256, 0, stream>>>(src, dst, offs, rank, srcs, degsum, bsumN, noffs);
    // 6. LDS-staged reorder -> node-major srcs2
    reorder2_kernel<<<(N_NODES + 255) / 256, 256, 0, stream>>>(offs, srcs, noffs, srcs2);

    // 7. gather1 (bf16 table): h1 -> h1r bf16 (bufB; rank dead)
    gather_flat_kernel<<<GATHER_BLOCKS, 256, 0, stream>>>(noffs, srcs2, dinv, hbuf, b1, bufB16, N_NODES);
    // 8. gemm2: h1r bf16 -> h2 fp8 (bufA region)
    gemm_mfma_fp8out_kernel<HIDDEN><<<GEMM_BLOCKS, 256, 0, stream>>>(bufB16, W2, hbuf8, N_NODES);
    // 9. gather2 (fp8 table): h2 -> out2 bf16 (bufB; h1r dead)
    gather_fp8_kernel<<<GATHER_BLOCKS, 256, 0, stream>>>(noffs, srcs2, dinv, hbuf8, b2, bufB16, N_NODES);

    // 10. pool + 11. head
    {
        const int chunk = 32;
        int waves  = (N_NODES + chunk - 1) / chunk;
        int blocks = (waves + 3) / 4;
        pool_kernel<<<blocks, 256, 0, stream>>>(bufB16, bat, pooled, cnt, N_NODES, chunk);
    }
    head_kernel<<<(N_GRAPHS + 255) / 256, 256, 0, stream>>>(pooled, cnt, Wfc, bfc, out);
}